// Round 4
// baseline (2456.547 us; speedup 1.0000x reference)
//
#include <hip/hip_runtime.h>

// VQ quantize: z [16,256,64,64] f32, weight [1024,256] f32.
// Outputs (f32, concat): quantized, straight_through (== quantized numerically), indices.
//
// Pass A (prep): z -> split bf16 (z = zhi + zlo), tiled [kc][g][n][8] for MFMA staging.
//                w -> whi/wlo tiled likewise; wn = numpy-replicated fp32 ||w||^2.
// Pass B: distance-argmin as a K=768 bf16 MFMA GEMM (zhi*whi + zhi*wlo + zlo*whi),
//         score error ~1e-6 << np's fp32 quantization shift (3.05e-5). Rows with
//         top-2 margin < TAU=1e-4 are flagged.
// Pass C: flagged rows get the round-3-validated numpy-bit-replicating rescore.
// Pass D: gather codebook rows into both outputs.
//
// Big scratch lives inside d_out: zhi+zlo exactly fill out0's 67MB (consumed before
// gather_k overwrites out0); w-tiles + wn sit in out1's region (overwritten last).

#define NROWS 65536
#define DDIM 256
#define KCODES 1024
#define TAU 1e-4f
#define RESCUE_CAP 16384

typedef unsigned short ushort_t;
typedef short bf16x8 __attribute__((ext_vector_type(8)));
typedef float f32x4 __attribute__((ext_vector_type(4)));

__device__ __forceinline__ ushort_t f2bf_rne(float x) {
    unsigned u = __float_as_uint(x);
    u += 0x7fffu + ((u >> 16) & 1u);
    return (ushort_t)(u >> 16);
}
__device__ __forceinline__ float bf2f(ushort_t h) {
    return __uint_as_float((unsigned)h << 16);
}
__device__ __forceinline__ void gld16(const void* g, void* l) {
    __builtin_amdgcn_global_load_lds((const __attribute__((address_space(1))) void*)g,
                                     (__attribute__((address_space(3))) void*)l, 16, 0, 0);
}

// numpy pairwise fp32 sum of 256 fl(x_i^2), streaming (no per-thread array):
// 128+128 split, 8 accumulators per half, fixed combine tree. Bit-matches np.sum.
template <typename F>
__device__ __forceinline__ float np_pairwise256_sq(F get) {
    float half[2];
#pragma unroll
    for (int h = 0; h < 2; ++h) {
        float r[8];
#pragma unroll
        for (int j = 0; j < 8; ++j) { float v = get(h * 128 + j); r[j] = __fmul_rn(v, v); }
        for (int i = 8; i < 128; i += 8)
#pragma unroll
            for (int j = 0; j < 8; ++j) {
                float v = get(h * 128 + i + j);
                r[j] = __fadd_rn(r[j], __fmul_rn(v, v));
            }
        half[h] = __fadd_rn(__fadd_rn(__fadd_rn(r[0], r[1]), __fadd_rn(r[2], r[3])),
                            __fadd_rn(__fadd_rn(r[4], r[5]), __fadd_rn(r[6], r[7])));
    }
    return __fadd_rn(half[0], half[1]);
}

// ---------------- prep: z -> zhi/zlo tiled [o=kc*4+g][n][8] ----------------
__global__ void zprep_k(const float* __restrict__ z, ushort_t* __restrict__ zhi,
                        ushort_t* __restrict__ zlo) {
    int tid = blockIdx.x * 256 + threadIdx.x;   // 2M threads
    int n = tid & 65535;
    int o = tid >> 16;                          // 0..31
    const float* zp = z + (size_t)(n >> 12) * 1048576 + (n & 4095);
    bf16x8 hv, lv;
#pragma unroll
    for (int j = 0; j < 8; ++j) {
        float v = zp[(size_t)(o * 8 + j) * 4096];
        ushort_t h = f2bf_rne(v);
        hv[j] = (short)h;
        lv[j] = (short)f2bf_rne(v - bf2f(h));
    }
    size_t off = ((size_t)o * 65536 + n) * 8;
    *reinterpret_cast<bf16x8*>(zhi + off) = hv;
    *reinterpret_cast<bf16x8*>(zlo + off) = lv;
}

// ---------------- prep: w -> whi/wlo tiled [o][c][8] ----------------
__global__ void wprep_k(const float* __restrict__ w, ushort_t* __restrict__ whi,
                        ushort_t* __restrict__ wlo) {
    int o = blockIdx.x;          // 0..31
    int c = threadIdx.x;         // 0..1023
    const float* wp = w + (size_t)c * DDIM + o * 8;
    bf16x8 hv, lv;
#pragma unroll
    for (int j = 0; j < 8; ++j) {
        float v = wp[j];
        ushort_t h = f2bf_rne(v);
        hv[j] = (short)h;
        lv[j] = (short)f2bf_rne(v - bf2f(h));
    }
    size_t off = ((size_t)o * 1024 + c) * 8;
    *reinterpret_cast<bf16x8*>(whi + off) = hv;
    *reinterpret_cast<bf16x8*>(wlo + off) = lv;
}

// ---------------- wn[k] = numpy-replicated fp32 ||w_k||^2 ----------------
__global__ void wnorm_k(const float* __restrict__ w, float* __restrict__ wn) {
    int k = blockIdx.x * 256 + threadIdx.x;
    const float* wp = w + (size_t)k * DDIM;
    wn[k] = np_pairwise256_sq([&](int i) { return wp[i]; });
}

// ---------------- fused bf16-MFMA distance + argmin ----------------
// Block: 128 rows x 1024 codes, 16 waves (wm = wid>>3 row-half, w8 = wid&7 code-block).
// K-loop: 24 steps of 32 (zhi*whi, zhi*wlo, zlo*whi). Staging via global_load_lds
// from pre-tiled buffers: LDS layout == global layout (linear, conflict-free frags).
__launch_bounds__(1024, 8)
__global__ void argmin_mfma_k(const ushort_t* __restrict__ zhi, const ushort_t* __restrict__ zlo,
                              const ushort_t* __restrict__ whi, const ushort_t* __restrict__ wlo,
                              const float* __restrict__ wn, float* __restrict__ idxf_out,
                              int* __restrict__ count, int* __restrict__ list) {
    __shared__ char arena[73728];     // [0,64K): W tile; [64K,72K): z tile; epilogue reuses [0,12K)
    char* lw = arena;
    char* lz = arena + 65536;
    const int t = threadIdx.x;
    const int lane = t & 63;
    const int l15 = lane & 15;
    const int l4  = lane >> 4;
    const int wid = t >> 6;
    const int wm = wid >> 3;
    const int w8 = wid & 7;
    const int n0 = blockIdx.x * 128;

    f32x4 acc[4][8];
#pragma unroll
    for (int mt = 0; mt < 4; ++mt)
#pragma unroll
        for (int nt = 0; nt < 8; ++nt) acc[mt][nt] = f32x4{0.f, 0.f, 0.f, 0.f};

    for (int ks = 0; ks < 24; ++ks) {
        const int kc = ks & 7;
        const ushort_t* ab = (ks < 16) ? zhi : zlo;
        const ushort_t* bb = (ks >= 8 && ks < 16) ? wlo : whi;
        __syncthreads();
        {   // stage W chunk: 64KB linear; wave wid covers 4KB
            const char* gs = (const char*)bb + (size_t)kc * 65536 + wid * 4096 + lane * 16;
            char* ld = lw + wid * 4096;
#pragma unroll
            for (int i = 0; i < 4; ++i) gld16(gs + i * 1024, ld + i * 1024);
        }
        if (wid < 4) {  // stage z chunk: 8KB; waves 0..3, 2KB each (g = wid)
            const char* gs = (const char*)ab + ((size_t)(kc * 4 + wid) * 65536 + n0) * 16 + lane * 16;
            char* ld = lz + wid * 2048;
#pragma unroll
            for (int i = 0; i < 2; ++i) gld16(gs + i * 1024, ld + i * 1024);
        }
        __syncthreads();
        // fragments: A row = wm*64+mt*16+l15, k = l4*8+j ; B col = w8*128+nt*16+l15
        bf16x8 a[4], b[8];
        const char* az = lz + l4 * 2048 + (wm * 64 + l15) * 16;
#pragma unroll
        for (int mt = 0; mt < 4; ++mt) a[mt] = *reinterpret_cast<const bf16x8*>(az + mt * 256);
        const char* bz = lw + l4 * 16384 + (w8 * 128 + l15) * 16;
#pragma unroll
        for (int nt = 0; nt < 8; ++nt) b[nt] = *reinterpret_cast<const bf16x8*>(bz + nt * 256);
#pragma unroll
        for (int mt = 0; mt < 4; ++mt)
#pragma unroll
            for (int nt = 0; nt < 8; ++nt)
                acc[mt][nt] = __builtin_amdgcn_mfma_f32_16x16x32_bf16(a[mt], b[nt], acc[mt][nt], 0, 0, 0);
    }

    // ---- epilogue: scores s = wn - 2*m, per-row top-2 ----
    float wnv[8];
#pragma unroll
    for (int nt = 0; nt < 8; ++nt) wnv[nt] = wn[w8 * 128 + nt * 16 + l15];

    __syncthreads();   // all compute done; safe to overlay red arrays onto arena
    float* redv = (float*)arena;            // [128][8]
    float* red2 = (float*)(arena + 4096);   // [128][8]
    int*   redi = (int*)(arena + 8192);     // [128][8]

#pragma unroll
    for (int mt = 0; mt < 4; ++mt) {
#pragma unroll
        for (int r = 0; r < 4; ++r) {
            // C/D layout (m89-verified): col=lane&15, row=(lane>>4)*4+r
            float bv = 3.4e38f, b2 = 3.4e38f;
            int bi = 0;
#pragma unroll
            for (int nt = 0; nt < 8; ++nt) {
                float s = fmaf(-2.f, acc[mt][nt][r], wnv[nt]);
                int c = w8 * 128 + nt * 16 + l15;
                if (s < bv) { b2 = bv; bv = s; bi = c; }
                else        { b2 = fminf(b2, s); }
            }
            // 16-lane butterfly within lane-group (all share the same row)
#pragma unroll
            for (int m = 1; m < 16; m <<= 1) {
                float ov = __shfl_xor(bv, m);
                int   oi = __shfl_xor(bi, m);
                float o2 = __shfl_xor(b2, m);
                if (ov < bv || (ov == bv && oi < bi)) { b2 = fminf(bv, o2); bv = ov; bi = oi; }
                else                                  { b2 = fminf(b2, ov); }
            }
            if (l15 == 0) {
                int row = wm * 64 + mt * 16 + l4 * 4 + r;
                redv[row * 8 + w8] = bv;
                red2[row * 8 + w8] = b2;
                redi[row * 8 + w8] = bi;
            }
        }
    }
    __syncthreads();
    if (t < 128) {
        float bv = redv[t * 8], b2 = red2[t * 8];
        int bi = redi[t * 8];
#pragma unroll
        for (int w = 1; w < 8; ++w) {
            float ov = redv[t * 8 + w], o2 = red2[t * 8 + w];
            int oi = redi[t * 8 + w];
            if (ov < bv || (ov == bv && oi < bi)) { b2 = fminf(bv, o2); bv = ov; bi = oi; }
            else                                  { b2 = fminf(b2, ov); }
        }
        int n = n0 + t;
        idxf_out[n] = (float)bi;
        if (b2 - bv < TAU) {
            int slot = atomicAdd(count, 1);
            if (slot < RESCUE_CAP) list[slot] = n;
        }
    }
}

// ---------------- rescue: bit-replicate numpy fp32 pipeline on flagged rows --------
__global__ void rescue_k(const float* __restrict__ z, const float* __restrict__ w,
                         const float* __restrict__ s2, const int* __restrict__ count,
                         const int* __restrict__ list, float* __restrict__ idxf_out) {
    __shared__ float zsh[DDIM];
    __shared__ float rdv[256];
    __shared__ int   rid[256];
    const int t = threadIdx.x;
    int cnt = *count;
    if (cnt > RESCUE_CAP) cnt = RESCUE_CAP;

    for (int s = blockIdx.x; s < cnt; s += gridDim.x) {
        int n = list[s];
        __syncthreads();
        zsh[t] = z[(size_t)(n >> 12) * 1048576 + (size_t)t * 4096 + (n & 4095)];
        __syncthreads();
        float s1 = np_pairwise256_sq([&](int i) { return zsh[i]; });

        float bv = 3.4e38f;
        int   bi = 0;
#pragma unroll
        for (int k = 0; k < 4; ++k) {
            int c = t * 4 + k;
            const float4* wp = reinterpret_cast<const float4*>(w + (size_t)c * DDIM);
            double md = 0.0;
            for (int j = 0; j < DDIM / 4; ++j) {
                float4 wv = wp[j];
                md = fma((double)zsh[j * 4 + 0], (double)wv.x, md);
                md = fma((double)zsh[j * 4 + 1], (double)wv.y, md);
                md = fma((double)zsh[j * 4 + 2], (double)wv.z, md);
                md = fma((double)zsh[j * 4 + 3], (double)wv.w, md);
            }
            float t1 = (float)((double)s1 - 2.0 * md);   // = fl32(s1 - 2m)
            float dq = __fadd_rn(t1, s2[c]);             // = fl32(t1 + s2)
            if (dq < bv) { bv = dq; bi = c; }
        }
        rdv[t] = bv; rid[t] = bi;
        __syncthreads();
        for (int off = 128; off > 0; off >>= 1) {
            if (t < off) {
                if (rdv[t + off] < rdv[t] ||
                    (rdv[t + off] == rdv[t] && rid[t + off] < rid[t])) {
                    rdv[t] = rdv[t + off]; rid[t] = rid[t + off];
                }
            }
            __syncthreads();
        }
        if (t == 0) idxf_out[n] = (float)rid[0];
    }
}

// ---------------- gather quantized = weight[idx] into [b,c,h,w] x2 ----------------
__global__ void gather_k(const float* __restrict__ idxf, const float* __restrict__ w,
                         float* __restrict__ out0, float* __restrict__ out1) {
    int tid = blockIdx.x * 256 + threadIdx.x;
    int n   = tid & 65535;
    int c4  = tid >> 16;
    int code = (int)idxf[n];
    float4 v = *reinterpret_cast<const float4*>(w + (size_t)code * DDIM + c4 * 4);
    size_t off = (size_t)(n >> 12) * 1048576 + (size_t)c4 * 4 * 4096 + (n & 4095);
    out0[off]         = v.x;
    out0[off + 4096]  = v.y;
    out0[off + 8192]  = v.z;
    out0[off + 12288] = v.w;
    out1[off]         = v.x;
    out1[off + 4096]  = v.y;
    out1[off + 8192]  = v.z;
    out1[off + 12288] = v.w;
}

extern "C" void kernel_launch(void* const* d_in, const int* in_sizes, int n_in,
                              void* d_out, int out_size, void* d_ws, size_t ws_size,
                              hipStream_t stream) {
    const float* z = (const float*)d_in[0];
    const float* w = (const float*)d_in[1];
    float* out    = (float*)d_out;
    float* out0   = out;
    float* out1   = out + 16777216;
    float* outidx = out + 33554432;

    // scratch inside d_out (consumed before gather_k overwrites):
    ushort_t* zhi = (ushort_t*)out0;                       // 32MB, exactly fills out0 with zlo
    ushort_t* zlo = (ushort_t*)out0 + 16777216;
    ushort_t* whi = (ushort_t*)out1;                       // 512KB
    ushort_t* wlo = (ushort_t*)out1 + 262144;              // 512KB
    float*    wn  = (float*)((char*)out1 + 1048576);       // 4KB
    int*   count = (int*)d_ws;
    int*   list  = (int*)((char*)d_ws + 4096);             // 64KB

    hipMemsetAsync(count, 0, sizeof(int), stream);
    wprep_k<<<32, 1024, 0, stream>>>(w, whi, wlo);
    wnorm_k<<<KCODES / 256, 256, 0, stream>>>(w, wn);
    zprep_k<<<NROWS * 32 / 256, 256, 0, stream>>>(z, zhi, zlo);
    argmin_mfma_k<<<NROWS / 128, 1024, 0, stream>>>(zhi, zlo, whi, wlo, wn, outidx, count, list);
    rescue_k<<<1024, 256, 0, stream>>>(z, w, wn, count, list, outidx);
    gather_k<<<NROWS * 64 / 256, 256, 0, stream>>>(outidx, w, out0, out1);
}

// Round 5
// 684.793 us; speedup vs baseline: 3.5873x; 3.5873x over previous
//
#include <hip/hip_runtime.h>

// VQ quantize: z [16,256,64,64] f32, weight [1024,256] f32.
// Outputs (f32, concat): quantized, straight_through (== quantized numerically), indices.
//
// Pass A (prep): z -> split bf16 (z = zhi + zlo), tiled [octet][n][8]; w likewise;
//                wn = numpy-replicated fp32 ||w||^2.
// Pass B: distance-argmin as bf16 MFMA GEMM (zhi*whi + zhi*wlo + zlo*whi), m97 geometry:
//         256 thr / 4 waves, 128x128 tile, BK=64, 32KB LDS, global_load_lds(16B).
//         Per-block top-2 partials -> [8][65536]; finalize_k merges + flags margin<TAU.
// Pass C: flagged rows -> numpy-bit-replicating fp64 rescore (validated in r3/r4).
// Pass D: gather codebook rows into both outputs.
//
// Scratch: zhi+zlo fill out0 (67MB, consumed before gather overwrites);
// w-tiles + wn + partials in out1 region; count/list in d_ws.

#define NROWS 65536
#define DDIM 256
#define KCODES 1024
#define TAU 2e-4f
#define RESCUE_CAP 16384

typedef unsigned short ushort_t;
typedef short bf16x8 __attribute__((ext_vector_type(8)));
typedef float f32x4 __attribute__((ext_vector_type(4)));

__device__ __forceinline__ ushort_t f2bf_rne(float x) {
    unsigned u = __float_as_uint(x);
    u += 0x7fffu + ((u >> 16) & 1u);
    return (ushort_t)(u >> 16);
}
__device__ __forceinline__ float bf2f(ushort_t h) {
    return __uint_as_float((unsigned)h << 16);
}
__device__ __forceinline__ void gld16(const void* g, void* l) {
    __builtin_amdgcn_global_load_lds((const __attribute__((address_space(1))) void*)g,
                                     (__attribute__((address_space(3))) void*)l, 16, 0, 0);
}

// numpy pairwise fp32 sum of 256 fl(x_i^2): 128+128 split, 8 accumulators per half,
// fixed combine tree. Bit-matches np.sum of the squared row.
template <typename F>
__device__ __forceinline__ float np_pairwise256_sq(F get) {
    float half[2];
#pragma unroll
    for (int h = 0; h < 2; ++h) {
        float r[8];
#pragma unroll
        for (int j = 0; j < 8; ++j) { float v = get(h * 128 + j); r[j] = __fmul_rn(v, v); }
        for (int i = 8; i < 128; i += 8)
#pragma unroll
            for (int j = 0; j < 8; ++j) {
                float v = get(h * 128 + i + j);
                r[j] = __fadd_rn(r[j], __fmul_rn(v, v));
            }
        half[h] = __fadd_rn(__fadd_rn(__fadd_rn(r[0], r[1]), __fadd_rn(r[2], r[3])),
                            __fadd_rn(__fadd_rn(r[4], r[5]), __fadd_rn(r[6], r[7])));
    }
    return __fadd_rn(half[0], half[1]);
}

// ---------------- prep: z -> zhi/zlo tiled [o=0..31][n][8] ----------------
__global__ void zprep_k(const float* __restrict__ z, ushort_t* __restrict__ zhi,
                        ushort_t* __restrict__ zlo) {
    int tid = blockIdx.x * 256 + threadIdx.x;
    int n = tid & 65535;
    int o = tid >> 16;
    const float* zp = z + (size_t)(n >> 12) * 1048576 + (n & 4095);
    bf16x8 hv, lv;
#pragma unroll
    for (int j = 0; j < 8; ++j) {
        float v = zp[(size_t)(o * 8 + j) * 4096];
        ushort_t h = f2bf_rne(v);
        hv[j] = (short)h;
        lv[j] = (short)f2bf_rne(v - bf2f(h));
    }
    size_t off = ((size_t)o * 65536 + n) * 8;
    *reinterpret_cast<bf16x8*>(zhi + off) = hv;
    *reinterpret_cast<bf16x8*>(zlo + off) = lv;
}

// ---------------- prep: w -> whi/wlo tiled [o][c][8] ----------------
__global__ void wprep_k(const float* __restrict__ w, ushort_t* __restrict__ whi,
                        ushort_t* __restrict__ wlo) {
    int o = blockIdx.x;          // 0..31
    int c = threadIdx.x;         // 0..1023
    const float* wp = w + (size_t)c * DDIM + o * 8;
    bf16x8 hv, lv;
#pragma unroll
    for (int j = 0; j < 8; ++j) {
        float v = wp[j];
        ushort_t h = f2bf_rne(v);
        hv[j] = (short)h;
        lv[j] = (short)f2bf_rne(v - bf2f(h));
    }
    size_t off = ((size_t)o * 1024 + c) * 8;
    *reinterpret_cast<bf16x8*>(whi + off) = hv;
    *reinterpret_cast<bf16x8*>(wlo + off) = lv;
}

// ---------------- wn[k] = numpy-replicated fp32 ||w_k||^2 ----------------
__global__ void wnorm_k(const float* __restrict__ w, float* __restrict__ wn) {
    int k = blockIdx.x * 256 + threadIdx.x;
    const float* wp = w + (size_t)k * DDIM;
    wn[k] = np_pairwise256_sq([&](int i) { return wp[i]; });
}

// ---------------- bf16-MFMA distance, m97 geometry, per-block top-2 partials --------
// Block: 128 rows x 128 codes; 4 waves 2x2 (wm row-half, wn_ code-half), 64x64 each.
// grid = 512 row-blocks x 8 code-blocks. 12 K-steps of BK=64 (3 split-passes x 4).
__launch_bounds__(256, 2)
__global__ void argmin_mfma_k(const ushort_t* __restrict__ zhi, const ushort_t* __restrict__ zlo,
                              const ushort_t* __restrict__ whi, const ushort_t* __restrict__ wlo,
                              const float* __restrict__ wn,
                              float* __restrict__ pv, float* __restrict__ p2,
                              int* __restrict__ pi) {
    __shared__ char lds[32768];                 // A tile 16KB | B tile 16KB
    char* lA = lds;
    char* lB = lds + 16384;
    const int t = threadIdx.x;
    const int lane = t & 63;
    const int l15 = lane & 15, l4 = lane >> 4;
    const int wid = t >> 6;                     // 0..3
    const int wm = wid >> 1, wn_ = wid & 1;
    const int cb = blockIdx.x & 7;
    const int n0 = (blockIdx.x >> 3) * 128;
    const int c0 = cb * 128;

    f32x4 acc[4][4];
#pragma unroll
    for (int mt = 0; mt < 4; ++mt)
#pragma unroll
        for (int nt = 0; nt < 4; ++nt) acc[mt][nt] = f32x4{0.f, 0.f, 0.f, 0.f};

#pragma unroll 1
    for (int p = 0; p < 3; ++p) {
        const ushort_t* ab = (p < 2) ? zhi : zlo;
        const ushort_t* bb = (p == 1) ? wlo : whi;
#pragma unroll 1
        for (int s = 0; s < 4; ++s) {
            __syncthreads();
            // stage A,B: 16 chunks x 1KB each; wave wid does chunks wid*4..wid*4+3
            // LDS layout: [octet_rel 0..7][row/col 0..127][8 bf16] (linear, == global tiling)
#pragma unroll
            for (int q = 0; q < 4; ++q) {
                int i = wid * 4 + q;
                int o = s * 8 + (i >> 1);
                int half = i & 1;
                gld16((const char*)ab + ((size_t)o * 65536 + n0 + half * 64) * 16 + lane * 16,
                      lA + i * 1024);
                gld16((const char*)bb + ((size_t)o * 1024 + c0 + half * 64) * 16 + lane * 16,
                      lB + i * 1024);
            }
            __syncthreads();
#pragma unroll
            for (int j = 0; j < 2; ++j) {
                bf16x8 a[4], b[4];
                const char* pa = lA + (j * 4 + l4) * 2048 + (wm * 64 + l15) * 16;
#pragma unroll
                for (int mt = 0; mt < 4; ++mt) a[mt] = *reinterpret_cast<const bf16x8*>(pa + mt * 256);
                const char* pb = lB + (j * 4 + l4) * 2048 + (wn_ * 64 + l15) * 16;
#pragma unroll
                for (int nt = 0; nt < 4; ++nt) b[nt] = *reinterpret_cast<const bf16x8*>(pb + nt * 256);
#pragma unroll
                for (int mt = 0; mt < 4; ++mt)
#pragma unroll
                    for (int nt = 0; nt < 4; ++nt)
                        acc[mt][nt] = __builtin_amdgcn_mfma_f32_16x16x32_bf16(a[mt], b[nt], acc[mt][nt], 0, 0, 0);
            }
        }
    }

    // ---- epilogue: s = wn - 2m; per-row top-2 over this block's 128 codes ----
    float wnv[4];
#pragma unroll
    for (int nt = 0; nt < 4; ++nt) wnv[nt] = wn[c0 + wn_ * 64 + nt * 16 + l15];

    __syncthreads();                            // LDS tiles dead; overlay reduce arrays
    float* redv = (float*)lds;                  // [128][2]
    float* red2 = (float*)(lds + 1024);
    int*   redi = (int*)(lds + 2048);

#pragma unroll
    for (int mt = 0; mt < 4; ++mt) {
#pragma unroll
        for (int r = 0; r < 4; ++r) {
            // C/D layout: col = lane&15, row = (lane>>4)*4 + r  (m89-verified, r4-confirmed)
            float bv = 3.4e38f, b2 = 3.4e38f;
            int bi = 0;
#pragma unroll
            for (int nt = 0; nt < 4; ++nt) {
                float s = fmaf(-2.f, acc[mt][nt][r], wnv[nt]);
                int c = c0 + wn_ * 64 + nt * 16 + l15;
                if (s < bv) { b2 = bv; bv = s; bi = c; }
                else        { b2 = fminf(b2, s); }
            }
#pragma unroll
            for (int m = 1; m < 16; m <<= 1) {  // 16-lane butterfly (within lane group)
                float ov = __shfl_xor(bv, m);
                int   oi = __shfl_xor(bi, m);
                float o2 = __shfl_xor(b2, m);
                if (ov < bv || (ov == bv && oi < bi)) { b2 = fminf(bv, o2); bv = ov; bi = oi; }
                else                                  { b2 = fminf(b2, ov); }
            }
            if (l15 == 0) {
                int row = wm * 64 + mt * 16 + l4 * 4 + r;
                redv[row * 2 + wn_] = bv;
                red2[row * 2 + wn_] = b2;
                redi[row * 2 + wn_] = bi;
            }
        }
    }
    __syncthreads();
    if (t < 128) {
        float bv = redv[t * 2], b2 = red2[t * 2];
        int   bi = redi[t * 2];
        float ov = redv[t * 2 + 1], o2 = red2[t * 2 + 1];
        int   oi = redi[t * 2 + 1];
        if (ov < bv) { b2 = fminf(bv, o2); bv = ov; bi = oi; }
        else         { b2 = fminf(b2, ov); }
        pv[cb * 65536 + n0 + t] = bv;
        p2[cb * 65536 + n0 + t] = b2;
        pi[cb * 65536 + n0 + t] = bi;
    }
}

// ---------------- finalize: merge 8 code-block partials, flag narrow margins --------
__global__ void finalize_k(const float* __restrict__ pv, const float* __restrict__ p2,
                           const int* __restrict__ pi, float* __restrict__ idxf_out,
                           int* __restrict__ count, int* __restrict__ list) {
    int n = blockIdx.x * 256 + threadIdx.x;
    float bv = 3.4e38f, b2 = 3.4e38f;
    int bi = 0;
#pragma unroll
    for (int cb = 0; cb < 8; ++cb) {            // ascending -> first-index tie semantics
        float ov = pv[cb * 65536 + n], o2 = p2[cb * 65536 + n];
        int oi = pi[cb * 65536 + n];
        if (ov < bv) { b2 = fminf(bv, o2); bv = ov; bi = oi; }
        else         { b2 = fminf(b2, fminf(ov, 3.4e38f)); }
    }
    idxf_out[n] = (float)bi;
    if (b2 - bv < TAU) {
        int slot = atomicAdd(count, 1);
        if (slot < RESCUE_CAP) list[slot] = n;
    }
}

// ---------------- rescue: bit-replicate numpy fp32 pipeline on flagged rows --------
__global__ void rescue_k(const float* __restrict__ z, const float* __restrict__ w,
                         const float* __restrict__ s2, const int* __restrict__ count,
                         const int* __restrict__ list, float* __restrict__ idxf_out) {
    __shared__ float zsh[DDIM];
    __shared__ float rdv[256];
    __shared__ int   rid[256];
    const int t = threadIdx.x;
    int cnt = *count;
    if (cnt > RESCUE_CAP) cnt = RESCUE_CAP;

    for (int s = blockIdx.x; s < cnt; s += gridDim.x) {
        int n = list[s];
        __syncthreads();
        zsh[t] = z[(size_t)(n >> 12) * 1048576 + (size_t)t * 4096 + (n & 4095)];
        __syncthreads();
        float s1 = np_pairwise256_sq([&](int i) { return zsh[i]; });

        float bv = 3.4e38f;
        int   bi = 0;
#pragma unroll
        for (int k = 0; k < 4; ++k) {
            int c = t * 4 + k;
            const float4* wp = reinterpret_cast<const float4*>(w + (size_t)c * DDIM);
            double md = 0.0;
            for (int j = 0; j < DDIM / 4; ++j) {
                float4 wv = wp[j];
                md = fma((double)zsh[j * 4 + 0], (double)wv.x, md);
                md = fma((double)zsh[j * 4 + 1], (double)wv.y, md);
                md = fma((double)zsh[j * 4 + 2], (double)wv.z, md);
                md = fma((double)zsh[j * 4 + 3], (double)wv.w, md);
            }
            float t1 = (float)((double)s1 - 2.0 * md);   // = fl32(s1 - 2m)
            float dq = __fadd_rn(t1, s2[c]);             // = fl32(t1 + s2)
            if (dq < bv) { bv = dq; bi = c; }
        }
        rdv[t] = bv; rid[t] = bi;
        __syncthreads();
        for (int off = 128; off > 0; off >>= 1) {
            if (t < off) {
                if (rdv[t + off] < rdv[t] ||
                    (rdv[t + off] == rdv[t] && rid[t + off] < rid[t])) {
                    rdv[t] = rdv[t + off]; rid[t] = rid[t + off];
                }
            }
            __syncthreads();
        }
        if (t == 0) idxf_out[n] = (float)rid[0];
    }
}

// ---------------- gather quantized = weight[idx] into [b,c,h,w] x2 ----------------
__global__ void gather_k(const float* __restrict__ idxf, const float* __restrict__ w,
                         float* __restrict__ out0, float* __restrict__ out1) {
    int tid = blockIdx.x * 256 + threadIdx.x;
    int n   = tid & 65535;
    int c4  = tid >> 16;
    int code = (int)idxf[n];
    float4 v = *reinterpret_cast<const float4*>(w + (size_t)code * DDIM + c4 * 4);
    size_t off = (size_t)(n >> 12) * 1048576 + (size_t)c4 * 4 * 4096 + (n & 4095);
    out0[off]         = v.x;
    out0[off + 4096]  = v.y;
    out0[off + 8192]  = v.z;
    out0[off + 12288] = v.w;
    out1[off]         = v.x;
    out1[off + 4096]  = v.y;
    out1[off + 8192]  = v.z;
    out1[off + 12288] = v.w;
}

extern "C" void kernel_launch(void* const* d_in, const int* in_sizes, int n_in,
                              void* d_out, int out_size, void* d_ws, size_t ws_size,
                              hipStream_t stream) {
    const float* z = (const float*)d_in[0];
    const float* w = (const float*)d_in[1];
    float* out    = (float*)d_out;
    float* out0   = out;
    float* out1   = out + 16777216;
    float* outidx = out + 33554432;

    // scratch inside d_out (consumed before gather_k overwrites):
    ushort_t* zhi = (ushort_t*)out0;                        // 33.5MB
    ushort_t* zlo = (ushort_t*)out0 + 16777216;             // 33.5MB (fills out0 exactly)
    char* s1b = (char*)out1;
    ushort_t* whi = (ushort_t*)s1b;                         // 512KB
    ushort_t* wlo = (ushort_t*)(s1b + 524288);              // 512KB
    float*    wn  = (float*)(s1b + 1048576);                // 4KB
    float*    pv  = (float*)(s1b + 2097152);                // 2MB
    float*    p2  = (float*)(s1b + 4194304);                // 2MB
    int*      pi  = (int*)(s1b + 6291456);                  // 2MB
    int*   count = (int*)d_ws;
    int*   list  = (int*)((char*)d_ws + 4096);              // 64KB

    hipMemsetAsync(count, 0, sizeof(int), stream);
    wprep_k<<<32, 1024, 0, stream>>>(w, whi, wlo);
    wnorm_k<<<KCODES / 256, 256, 0, stream>>>(w, wn);
    zprep_k<<<NROWS * 32 / 256, 256, 0, stream>>>(z, zhi, zlo);
    argmin_mfma_k<<<(NROWS / 128) * 8, 256, 0, stream>>>(zhi, zlo, whi, wlo, wn, pv, p2, pi);
    finalize_k<<<NROWS / 256, 256, 0, stream>>>(pv, p2, pi, outidx, count, list);
    rescue_k<<<1024, 256, 0, stream>>>(z, w, wn, count, list, outidx);
    gather_k<<<NROWS * 64 / 256, 256, 0, stream>>>(outidx, w, out0, out1);
}

// Round 6
// 235.691 us; speedup vs baseline: 10.4228x; 2.9055x over previous
//
#include <hip/hip_runtime.h>

// VQ quantize: z [16,256,64,64] f32, weight [1024,256] f32.
// Outputs (f32, concat): quantized, straight_through (== quantized numerically), indices.
//
// Pass A (prep): z -> split bf16 (z = zhi + zlo) tiled [o][n][8]; w likewise;
//                wn = numpy-replicated fp32 ||w||^2.
// Pass B: distance-argmin as bf16 MFMA GEMM (zhi*whi + zhi*wlo + zlo*whi), m97 geometry.
//         Epilogue per (row, 64-code entry): top-1 (value, code) + 64-bit mask of codes
//         within W of the entry top-1.
// Pass C (finalize): global top-1 (ascending -> np first-index ties); flag rows whose
//         margin < TAU (cross-entry top1 or in-entry mask popcount>1).
// Pass D (rescue): 1 wave per flagged row; np-bit-replicating rescore of ONLY the
//         candidate codes (entries with top1 <= gmin+TAU, their mask bits).
// Pass E: gather codebook rows into both outputs.

#define NROWS 65536
#define DDIM 256
#define KCODES 1024
#define TAU 1.5e-4f
#define WWIN 2e-4f

typedef unsigned short ushort_t;
typedef unsigned long long u64;
typedef short bf16x8 __attribute__((ext_vector_type(8)));
typedef float f32x4 __attribute__((ext_vector_type(4)));

__device__ __forceinline__ ushort_t f2bf_rne(float x) {
    unsigned u = __float_as_uint(x);
    u += 0x7fffu + ((u >> 16) & 1u);
    return (ushort_t)(u >> 16);
}
__device__ __forceinline__ float bf2f(ushort_t h) {
    return __uint_as_float((unsigned)h << 16);
}
__device__ __forceinline__ void gld16(const void* g, void* l) {
    __builtin_amdgcn_global_load_lds((const __attribute__((address_space(1))) void*)g,
                                     (__attribute__((address_space(3))) void*)l, 16, 0, 0);
}

// numpy pairwise fp32 sum of 256 fl(x_i^2): 128+128 split, 8 accumulators per half,
// fixed combine tree. Bit-matches np.sum(flat*flat, axis=1) (validated r3/r5).
template <typename F>
__device__ __forceinline__ float np_pairwise256_sq(F get) {
    float half[2];
#pragma unroll
    for (int h = 0; h < 2; ++h) {
        float r[8];
#pragma unroll
        for (int j = 0; j < 8; ++j) { float v = get(h * 128 + j); r[j] = __fmul_rn(v, v); }
        for (int i = 8; i < 128; i += 8)
#pragma unroll
            for (int j = 0; j < 8; ++j) {
                float v = get(h * 128 + i + j);
                r[j] = __fadd_rn(r[j], __fmul_rn(v, v));
            }
        half[h] = __fadd_rn(__fadd_rn(__fadd_rn(r[0], r[1]), __fadd_rn(r[2], r[3])),
                            __fadd_rn(__fadd_rn(r[4], r[5]), __fadd_rn(r[6], r[7])));
    }
    return __fadd_rn(half[0], half[1]);
}

// ---------------- prep: z -> zhi/zlo tiled [o=0..31][n][8] ----------------
__global__ void zprep_k(const float* __restrict__ z, ushort_t* __restrict__ zhi,
                        ushort_t* __restrict__ zlo) {
    int tid = blockIdx.x * 256 + threadIdx.x;
    int n = tid & 65535;
    int o = tid >> 16;
    const float* zp = z + (size_t)(n >> 12) * 1048576 + (n & 4095);
    bf16x8 hv, lv;
#pragma unroll
    for (int j = 0; j < 8; ++j) {
        float v = zp[(size_t)(o * 8 + j) * 4096];
        ushort_t h = f2bf_rne(v);
        hv[j] = (short)h;
        lv[j] = (short)f2bf_rne(v - bf2f(h));
    }
    size_t off = ((size_t)o * 65536 + n) * 8;
    *reinterpret_cast<bf16x8*>(zhi + off) = hv;
    *reinterpret_cast<bf16x8*>(zlo + off) = lv;
}

// ---------------- prep: w -> whi/wlo tiled [o][c][8] ----------------
__global__ void wprep_k(const float* __restrict__ w, ushort_t* __restrict__ whi,
                        ushort_t* __restrict__ wlo) {
    int o = blockIdx.x;          // 0..31
    int c = threadIdx.x;         // 0..1023
    const float* wp = w + (size_t)c * DDIM + o * 8;
    bf16x8 hv, lv;
#pragma unroll
    for (int j = 0; j < 8; ++j) {
        float v = wp[j];
        ushort_t h = f2bf_rne(v);
        hv[j] = (short)h;
        lv[j] = (short)f2bf_rne(v - bf2f(h));
    }
    size_t off = ((size_t)o * 1024 + c) * 8;
    *reinterpret_cast<bf16x8*>(whi + off) = hv;
    *reinterpret_cast<bf16x8*>(wlo + off) = lv;
}

// ---------------- wn[k] = numpy-replicated fp32 ||w_k||^2 ----------------
__global__ void wnorm_k(const float* __restrict__ w, float* __restrict__ wn) {
    int k = blockIdx.x * 256 + threadIdx.x;
    const float* wp = w + (size_t)k * DDIM;
    wn[k] = np_pairwise256_sq([&](int i) { return wp[i]; });
}

// ---------------- bf16-MFMA distance; per-(row, 64-code entry) top1 + W-mask --------
// Block: 128 rows x 128 codes; 4 waves 2x2 (wm row-half, wn_ code-half), 64x64 each.
// grid = 512 row-blocks x 8 code-blocks. 12 K-steps of BK=64 (3 split-passes x 4).
__launch_bounds__(256, 2)
__global__ void argmin_mfma_k(const ushort_t* __restrict__ zhi, const ushort_t* __restrict__ zlo,
                              const ushort_t* __restrict__ whi, const ushort_t* __restrict__ wlo,
                              const float* __restrict__ wn,
                              float* __restrict__ btv, int* __restrict__ bti,
                              u64* __restrict__ bmk) {
    __shared__ char lds[32768];                 // A tile 16KB | B tile 16KB
    char* lA = lds;
    char* lB = lds + 16384;
    const int t = threadIdx.x;
    const int lane = t & 63;
    const int l15 = lane & 15, l4 = lane >> 4;
    const int wid = t >> 6;                     // 0..3
    const int wm = wid >> 1, wn_ = wid & 1;
    const int cb = blockIdx.x & 7;
    const int n0 = (blockIdx.x >> 3) * 128;
    const int c0 = cb * 128;

    f32x4 acc[4][4];
#pragma unroll
    for (int mt = 0; mt < 4; ++mt)
#pragma unroll
        for (int nt = 0; nt < 4; ++nt) acc[mt][nt] = f32x4{0.f, 0.f, 0.f, 0.f};

#pragma unroll 1
    for (int p = 0; p < 3; ++p) {
        const ushort_t* ab = (p < 2) ? zhi : zlo;
        const ushort_t* bb = (p == 1) ? wlo : whi;
#pragma unroll 1
        for (int s = 0; s < 4; ++s) {
            __syncthreads();
            // stage A,B: 16 chunks x 1KB each; wave wid does chunks wid*4..wid*4+3
#pragma unroll
            for (int q = 0; q < 4; ++q) {
                int i = wid * 4 + q;
                int o = s * 8 + (i >> 1);
                int half = i & 1;
                gld16((const char*)ab + ((size_t)o * 65536 + n0 + half * 64) * 16 + lane * 16,
                      lA + i * 1024);
                gld16((const char*)bb + ((size_t)o * 1024 + c0 + half * 64) * 16 + lane * 16,
                      lB + i * 1024);
            }
            __syncthreads();
#pragma unroll
            for (int j = 0; j < 2; ++j) {
                bf16x8 a[4], b[4];
                const char* pa = lA + (j * 4 + l4) * 2048 + (wm * 64 + l15) * 16;
#pragma unroll
                for (int mt = 0; mt < 4; ++mt) a[mt] = *reinterpret_cast<const bf16x8*>(pa + mt * 256);
                const char* pb = lB + (j * 4 + l4) * 2048 + (wn_ * 64 + l15) * 16;
#pragma unroll
                for (int nt = 0; nt < 4; ++nt) b[nt] = *reinterpret_cast<const bf16x8*>(pb + nt * 256);
#pragma unroll
                for (int mt = 0; mt < 4; ++mt)
#pragma unroll
                    for (int nt = 0; nt < 4; ++nt)
                        acc[mt][nt] = __builtin_amdgcn_mfma_f32_16x16x32_bf16(a[mt], b[nt], acc[mt][nt], 0, 0, 0);
            }
        }
    }

    // ---- epilogue: s = wn - 2m; per (row, entry e=cb*2+wn_): top1 + W-window mask ----
    float wnv[4];
#pragma unroll
    for (int nt = 0; nt < 4; ++nt) wnv[nt] = wn[c0 + wn_ * 64 + nt * 16 + l15];
    const int ebase = ((cb << 1) | wn_) << 16;

#pragma unroll
    for (int mt = 0; mt < 4; ++mt) {
#pragma unroll
        for (int r = 0; r < 4; ++r) {
            // C/D layout: col = lane&15, row = (lane>>4)*4 + r
            float s[4];
            float bv = 3.4e38f;
            int   bc = 0;
#pragma unroll
            for (int nt = 0; nt < 4; ++nt) {
                s[nt] = fmaf(-2.f, acc[mt][nt][r], wnv[nt]);
                if (s[nt] < bv) { bv = s[nt]; bc = c0 + wn_ * 64 + nt * 16 + l15; }
            }
#pragma unroll
            for (int mm = 1; mm < 16; mm <<= 1) {   // top-1 butterfly within 16-lane group
                float ov = __shfl_xor(bv, mm);
                int   oc = __shfl_xor(bc, mm);
                if (ov < bv || (ov == bv && oc < bc)) { bv = ov; bc = oc; }
            }
            u64 msk = 0;
#pragma unroll
            for (int nt = 0; nt < 4; ++nt) {        // wave ballot; nibble per l4 group
                u64 bal = __ballot(s[nt] < bv + WWIN);
                msk |= ((bal >> (16 * l4)) & 0xFFFFull) << (16 * nt);
            }
            if (l15 == 0) {
                int row = wm * 64 + mt * 16 + l4 * 4 + r;
                btv[ebase + n0 + row] = bv;
                bti[ebase + n0 + row] = bc;
                bmk[ebase + n0 + row] = msk;
            }
        }
    }
}

// ---------------- finalize: global top-1, flag narrow-margin rows ----------------
__global__ void finalize_k(const float* __restrict__ btv, const int* __restrict__ bti,
                           const u64* __restrict__ bmk, float* __restrict__ idxf_out,
                           int* __restrict__ count, int* __restrict__ list) {
    int n = blockIdx.x * 256 + threadIdx.x;
    float gv = 3.4e38f;
    int   gi = 0, ge = 0;
#pragma unroll
    for (int e = 0; e < 16; ++e) {              // ascending e == ascending codes
        float v = btv[(e << 16) + n];
        int   c = bti[(e << 16) + n];
        if (v < gv || (v == gv && c < gi)) { gv = v; gi = c; ge = e; }
    }
    float sec = 3.4e38f;
#pragma unroll
    for (int e = 0; e < 16; ++e) {
        float v = btv[(e << 16) + n];
        if (e != ge) sec = fminf(sec, v);
    }
    int pc = __popcll(bmk[(ge << 16) + n]);
    idxf_out[n] = (float)gi;
    if (pc > 1 || sec - gv < TAU) {
        int slot = atomicAdd(count, 1);
        list[slot] = n;                         // list sized 65536: cannot overflow
    }
}

// ---------------- rescue: np-replicate ONLY candidate codes of flagged rows --------
// 1 wave per row. Candidates: entries with top1 <= gmin+TAU, their W-mask bits.
__global__ void rescue_k(const float* __restrict__ z, const float* __restrict__ w,
                         const float* __restrict__ s2, const float* __restrict__ btv,
                         const u64* __restrict__ bmk, const int* __restrict__ count,
                         const int* __restrict__ list, float* __restrict__ idxf_out) {
    __shared__ float zsh[DDIM];
    const int lane = threadIdx.x;               // 0..63
    int cnt = *count;

    for (int s = blockIdx.x; s < cnt; s += gridDim.x) {
        int n = list[s];
        const float* zp = z + (size_t)(n >> 12) * 1048576 + (n & 4095);
        float zr[4];
        __syncthreads();
#pragma unroll
        for (int j = 0; j < 4; ++j) {
            zr[j] = zp[(size_t)(lane * 4 + j) * 4096];
            zsh[lane * 4 + j] = zr[j];
        }
        __syncthreads();
        float s1 = np_pairwise256_sq([&](int i) { return zsh[i]; });

        float gv = 3.4e38f;
#pragma unroll
        for (int e = 0; e < 16; ++e) gv = fminf(gv, btv[(e << 16) + n]);

        float bv = 3.4e38f;
        int   bi = 0;
        for (int e = 0; e < 16; ++e) {          // ascending codes -> first-index ties
            float tv = btv[(e << 16) + n];
            if (tv <= gv + TAU) {
                u64 m = bmk[(e << 16) + n];
                while (m) {
                    int k = __ffsll(m) - 1;     // lowest bit first -> ascending
                    m &= m - 1;
                    int c = (e >> 1) * 128 + (e & 1) * 64 + k;
                    const float* wp = w + (size_t)c * DDIM + lane * 4;
                    double md = 0.0;
#pragma unroll
                    for (int j = 0; j < 4; ++j) md = fma((double)zr[j], (double)wp[j], md);
#pragma unroll
                    for (int mm = 1; mm < 64; mm <<= 1) md += __shfl_xor(md, mm);
                    float dq = __fadd_rn((float)((double)s1 - 2.0 * md), s2[c]);
                    if (dq < bv) { bv = dq; bi = c; }
                }
            }
        }
        if (lane == 0) idxf_out[n] = (float)bi;
    }
}

// ---------------- gather quantized = weight[idx] into [b,c,h,w] x2 ----------------
__global__ void gather_k(const float* __restrict__ idxf, const float* __restrict__ w,
                         float* __restrict__ out0, float* __restrict__ out1) {
    int tid = blockIdx.x * 256 + threadIdx.x;
    int n   = tid & 65535;
    int c4  = tid >> 16;
    int code = (int)idxf[n];
    float4 v = *reinterpret_cast<const float4*>(w + (size_t)code * DDIM + c4 * 4);
    size_t off = (size_t)(n >> 12) * 1048576 + (size_t)c4 * 4 * 4096 + (n & 4095);
    out0[off]         = v.x;
    out0[off + 4096]  = v.y;
    out0[off + 8192]  = v.z;
    out0[off + 12288] = v.w;
    out1[off]         = v.x;
    out1[off + 4096]  = v.y;
    out1[off + 8192]  = v.z;
    out1[off + 12288] = v.w;
}

extern "C" void kernel_launch(void* const* d_in, const int* in_sizes, int n_in,
                              void* d_out, int out_size, void* d_ws, size_t ws_size,
                              hipStream_t stream) {
    const float* z = (const float*)d_in[0];
    const float* w = (const float*)d_in[1];
    float* out    = (float*)d_out;
    float* out0   = out;
    float* out1   = out + 16777216;
    float* outidx = out + 33554432;

    // scratch inside d_out (consumed before gather_k overwrites):
    ushort_t* zhi = (ushort_t*)out0;                        // 33.5MB
    ushort_t* zlo = (ushort_t*)out0 + 16777216;             // 33.5MB (fills out0 exactly)
    char* s1b = (char*)out1;
    ushort_t* whi = (ushort_t*)s1b;                         // 512KB @ 0
    ushort_t* wlo = (ushort_t*)(s1b + 524288);              // 512KB
    float*    wn  = (float*)(s1b + 1048576);                // 4KB
    float*    btv = (float*)(s1b + 2097152);                // 4MB  [16][65536]
    int*      bti = (int*)(s1b + 6291456);                  // 4MB  [16][65536]
    u64*      bmk = (u64*)(s1b + 10485760);                 // 8MB  [16][65536]
    int*      list = (int*)(s1b + 18874368);                // 256KB [65536]
    int*   count = (int*)d_ws;

    hipMemsetAsync(count, 0, sizeof(int), stream);
    wprep_k<<<32, 1024, 0, stream>>>(w, whi, wlo);
    wnorm_k<<<KCODES / 256, 256, 0, stream>>>(w, wn);
    zprep_k<<<NROWS * 32 / 256, 256, 0, stream>>>(z, zhi, zlo);
    argmin_mfma_k<<<(NROWS / 128) * 8, 256, 0, stream>>>(zhi, zlo, whi, wlo, wn, btv, bti, bmk);
    finalize_k<<<NROWS / 256, 256, 0, stream>>>(btv, bti, bmk, outidx, count, list);
    rescue_k<<<4096, 64, 0, stream>>>(z, w, wn, btv, bmk, count, list, outidx);
    gather_k<<<NROWS * 64 / 256, 256, 0, stream>>>(outidx, w, out0, out1);
}

// Round 7
// 177.401 us; speedup vs baseline: 13.8474x; 1.3286x over previous
//
#include <hip/hip_runtime.h>

// VQ quantize: z [16,256,64,64] f32, weight [1024,256] f32.
// Outputs (f32, concat): quantized, straight_through (== quantized numerically), indices.
//
// Pass A (prep): z -> fp16 tiled [o][n][8]; w -> fp16 (x1024, exact pow2) tiled;
//                wn = numpy-replicated fp32 ||w||^2.
// Pass B: distance scores s = wn - 2^-9 * (z16 . w16') via ONE fp16 MFMA pass
//         (score err ~7e-6 rms << np quant shift 6.1e-5). Per (row, 64-code entry):
//         top-1 (value, code) + 64-bit mask of codes within W of entry top-1.
// Pass C (finalize): global top-1 (ascending -> np first-index ties); flags byte per row:
//         margin < TAU (cross-entry) or in-entry popcount>1.
// Pass D (rescue): 1 wave per 16-row group, early-exit on flags, cooperative z panel;
//         np-bit-replicating rescore of ONLY candidate codes. TAU=W=2e-4 >= Q+2E.
// Pass E: gather codebook rows into both outputs.

#define NROWS 65536
#define DDIM 256
#define KCODES 1024
#define TAU 2e-4f
#define WWIN 2e-4f

typedef unsigned short ushort_t;
typedef unsigned long long u64;
typedef _Float16 f16x8 __attribute__((ext_vector_type(8)));
typedef float f32x4 __attribute__((ext_vector_type(4)));

__device__ __forceinline__ void gld16(const void* g, void* l) {
    __builtin_amdgcn_global_load_lds((const __attribute__((address_space(1))) void*)g,
                                     (__attribute__((address_space(3))) void*)l, 16, 0, 0);
}

// numpy pairwise fp32 sum of 256 fl(x_i^2): 128+128 split, 8 accumulators per half,
// fixed combine tree. Bit-matches np.sum(flat*flat, axis=1) (validated r3/r5/r6).
template <typename F>
__device__ __forceinline__ float np_pairwise256_sq(F get) {
    float half[2];
#pragma unroll
    for (int h = 0; h < 2; ++h) {
        float r[8];
#pragma unroll
        for (int j = 0; j < 8; ++j) { float v = get(h * 128 + j); r[j] = __fmul_rn(v, v); }
        for (int i = 8; i < 128; i += 8)
#pragma unroll
            for (int j = 0; j < 8; ++j) {
                float v = get(h * 128 + i + j);
                r[j] = __fadd_rn(r[j], __fmul_rn(v, v));
            }
        half[h] = __fadd_rn(__fadd_rn(__fadd_rn(r[0], r[1]), __fadd_rn(r[2], r[3])),
                            __fadd_rn(__fadd_rn(r[4], r[5]), __fadd_rn(r[6], r[7])));
    }
    return __fadd_rn(half[0], half[1]);
}

// ---------------- prep: z -> z16 tiled [o=0..31][n][8] ----------------
__global__ void zprep_k(const float* __restrict__ z, f16x8* __restrict__ z16) {
    int tid = blockIdx.x * 256 + threadIdx.x;
    int n = tid & 65535;
    int o = tid >> 16;
    const float* zp = z + (size_t)(n >> 12) * 1048576 + (n & 4095);
    f16x8 hv;
#pragma unroll
    for (int j = 0; j < 8; ++j) hv[j] = (_Float16)zp[(size_t)(o * 8 + j) * 4096];
    z16[(size_t)o * 65536 + n] = hv;
}

// ---------------- prep: w -> w16 = fl16(1024*w) tiled [o][c][8] ----------------
__global__ void wprep_k(const float* __restrict__ w, f16x8* __restrict__ w16) {
    int o = blockIdx.x;          // 0..31
    int c = threadIdx.x;         // 0..1023
    const float* wp = w + (size_t)c * DDIM + o * 8;
    f16x8 hv;
#pragma unroll
    for (int j = 0; j < 8; ++j) hv[j] = (_Float16)(wp[j] * 1024.0f);   // pow2 scale: exact
    w16[(size_t)o * 1024 + c] = hv;
}

// ---------------- wn[k] = numpy-replicated fp32 ||w_k||^2 ----------------
__global__ void wnorm_k(const float* __restrict__ w, float* __restrict__ wn) {
    int k = blockIdx.x * 256 + threadIdx.x;
    const float* wp = w + (size_t)k * DDIM;
    wn[k] = np_pairwise256_sq([&](int i) { return wp[i]; });
}

// ---------------- fp16-MFMA distance; per-(row, 64-code entry) top1 + W-mask --------
// Block: 128 rows x 128 codes; 4 waves 2x2 (wm row-half, wn_ code-half), 64x64 each.
// grid = 512 row-blocks x 8 code-blocks. 4 K-steps of BK=64.
__launch_bounds__(256, 2)
__global__ void argmin_mfma_k(const f16x8* __restrict__ z16, const f16x8* __restrict__ w16,
                              const float* __restrict__ wn,
                              float* __restrict__ btv, int* __restrict__ bti,
                              u64* __restrict__ bmk) {
    __shared__ char lds[32768];                 // A tile 16KB | B tile 16KB
    char* lA = lds;
    char* lB = lds + 16384;
    const int t = threadIdx.x;
    const int lane = t & 63;
    const int l15 = lane & 15, l4 = lane >> 4;
    const int wid = t >> 6;                     // 0..3
    const int wm = wid >> 1, wn_ = wid & 1;
    const int cb = blockIdx.x & 7;
    const int n0 = (blockIdx.x >> 3) * 128;
    const int c0 = cb * 128;

    f32x4 acc[4][4];
#pragma unroll
    for (int mt = 0; mt < 4; ++mt)
#pragma unroll
        for (int nt = 0; nt < 4; ++nt) acc[mt][nt] = f32x4{0.f, 0.f, 0.f, 0.f};

#pragma unroll 1
    for (int s = 0; s < 4; ++s) {
        __syncthreads();
        // stage A,B: 16 chunks x 1KB each; wave wid does chunks wid*4..wid*4+3
        // LDS layout: [octet_rel 0..7][row/col 0..127][8 f16] (linear == global tiling)
#pragma unroll
        for (int q = 0; q < 4; ++q) {
            int i = wid * 4 + q;
            int o = s * 8 + (i >> 1);
            int half = i & 1;
            gld16((const char*)z16 + ((size_t)o * 65536 + n0 + half * 64) * 16 + lane * 16,
                  lA + i * 1024);
            gld16((const char*)w16 + ((size_t)o * 1024 + c0 + half * 64) * 16 + lane * 16,
                  lB + i * 1024);
        }
        __syncthreads();
#pragma unroll
        for (int j = 0; j < 2; ++j) {
            f16x8 a[4], b[4];
            const char* pa = lA + (j * 4 + l4) * 2048 + (wm * 64 + l15) * 16;
#pragma unroll
            for (int mt = 0; mt < 4; ++mt) a[mt] = *reinterpret_cast<const f16x8*>(pa + mt * 256);
            const char* pb = lB + (j * 4 + l4) * 2048 + (wn_ * 64 + l15) * 16;
#pragma unroll
            for (int nt = 0; nt < 4; ++nt) b[nt] = *reinterpret_cast<const f16x8*>(pb + nt * 256);
#pragma unroll
            for (int mt = 0; mt < 4; ++mt)
#pragma unroll
                for (int nt = 0; nt < 4; ++nt)
                    acc[mt][nt] = __builtin_amdgcn_mfma_f32_16x16x32_f16(a[mt], b[nt], acc[mt][nt], 0, 0, 0);
        }
    }

    // ---- epilogue: s = wn - 2^-9 m'; per (row, entry e=cb*2+wn_): top1 + W-mask ----
    float wnv[4];
#pragma unroll
    for (int nt = 0; nt < 4; ++nt) wnv[nt] = wn[c0 + wn_ * 64 + nt * 16 + l15];
    const int ebase = ((cb << 1) | wn_) << 16;

#pragma unroll
    for (int mt = 0; mt < 4; ++mt) {
#pragma unroll
        for (int r = 0; r < 4; ++r) {
            // C/D layout: col = lane&15, row = (lane>>4)*4 + r
            float s[4];
            float bv = 3.4e38f;
            int   bc = 0;
#pragma unroll
            for (int nt = 0; nt < 4; ++nt) {
                s[nt] = fmaf(-0.001953125f, acc[mt][nt][r], wnv[nt]);   // -2^-9 (w scaled x1024)
                if (s[nt] < bv) { bv = s[nt]; bc = c0 + wn_ * 64 + nt * 16 + l15; }
            }
#pragma unroll
            for (int mm = 1; mm < 16; mm <<= 1) {   // top-1 butterfly within 16-lane group
                float ov = __shfl_xor(bv, mm);
                int   oc = __shfl_xor(bc, mm);
                if (ov < bv || (ov == bv && oc < bc)) { bv = ov; bc = oc; }
            }
            u64 msk = 0;
#pragma unroll
            for (int nt = 0; nt < 4; ++nt) {        // wave ballot; 16-bit slice per l4 group
                u64 bal = __ballot(s[nt] < bv + WWIN);
                msk |= ((bal >> (16 * l4)) & 0xFFFFull) << (16 * nt);
            }
            if (l15 == 0) {
                int row = wm * 64 + mt * 16 + l4 * 4 + r;
                btv[ebase + n0 + row] = bv;
                bti[ebase + n0 + row] = bc;
                bmk[ebase + n0 + row] = msk;
            }
        }
    }
}

// ---------------- finalize: global top-1, flag narrow-margin rows ----------------
__global__ void finalize_k(const float* __restrict__ btv, const int* __restrict__ bti,
                           const u64* __restrict__ bmk, float* __restrict__ idxf_out,
                           unsigned char* __restrict__ flags) {
    int n = blockIdx.x * 256 + threadIdx.x;
    float gv = 3.4e38f;
    int   gi = 0, ge = 0;
#pragma unroll
    for (int e = 0; e < 16; ++e) {              // ascending e == ascending codes
        float v = btv[(e << 16) + n];
        int   c = bti[(e << 16) + n];
        if (v < gv || (v == gv && c < gi)) { gv = v; gi = c; ge = e; }
    }
    float sec = 3.4e38f;
#pragma unroll
    for (int e = 0; e < 16; ++e) {
        float v = btv[(e << 16) + n];
        if (e != ge) sec = fminf(sec, v);
    }
    int pc = __popcll(bmk[(ge << 16) + n]);
    idxf_out[n] = (float)gi;
    flags[n] = (pc > 1 || sec - gv < TAU) ? 1 : 0;
}

// ---------------- rescue: grouped (16 rows/wave), candidates only ----------------
__global__ void rescue_k(const float* __restrict__ z, const float* __restrict__ w,
                         const float* __restrict__ s2, const float* __restrict__ btv,
                         const u64* __restrict__ bmk, const unsigned char* __restrict__ flags,
                         float* __restrict__ idxf_out) {
    __shared__ float zsh[16][256];              // 16KB panel
    const int n0 = blockIdx.x * 16;
    const int lane = threadIdx.x;               // 0..63

    const u64* fp = reinterpret_cast<const u64*>(flags + n0);
    if ((fp[0] | fp[1]) == 0) return;           // no flagged rows in this line-group

    // cooperative panel load: rows n0..n0+15 (share the same 64B z-lines)
    const float* zb = z + (size_t)(n0 >> 12) * 1048576 + (n0 & 4095);
#pragma unroll
    for (int it = 0; it < 16; ++it) {
        int d = it * 16 + (lane >> 2);
        float4 v = *reinterpret_cast<const float4*>(zb + (size_t)d * 4096 + (lane & 3) * 4);
        zsh[(lane & 3) * 4 + 0][d] = v.x;
        zsh[(lane & 3) * 4 + 1][d] = v.y;
        zsh[(lane & 3) * 4 + 2][d] = v.z;
        zsh[(lane & 3) * 4 + 3][d] = v.w;
    }
    __syncthreads();

    for (int r = 0; r < 16; ++r) {
        if (!flags[n0 + r]) continue;
        int n = n0 + r;
        float s1 = np_pairwise256_sq([&](int i) { return zsh[r][i]; });
        float gv = 3.4e38f;
#pragma unroll
        for (int e = 0; e < 16; ++e) gv = fminf(gv, btv[(e << 16) + n]);

        float bv = 3.4e38f;
        int   bi = 0;
        for (int e = 0; e < 16; ++e) {          // ascending codes -> first-index ties
            float tv = btv[(e << 16) + n];
            if (tv <= gv + TAU) {
                u64 m = bmk[(e << 16) + n];
                while (m) {
                    int k = __ffsll((long long)m) - 1;   // lowest bit first -> ascending
                    m &= m - 1;
                    int c = e * 64 + k;
                    const float* wp = w + (size_t)c * DDIM + lane * 4;
                    double md = 0.0;
#pragma unroll
                    for (int j = 0; j < 4; ++j)
                        md = fma((double)zsh[r][lane * 4 + j], (double)wp[j], md);
#pragma unroll
                    for (int mm = 1; mm < 64; mm <<= 1) md += __shfl_xor(md, mm);
                    float dq = __fadd_rn((float)((double)s1 - 2.0 * md), s2[c]);
                    if (dq < bv) { bv = dq; bi = c; }
                }
            }
        }
        if (lane == 0) idxf_out[n] = (float)bi;
    }
}

// ---------------- gather quantized = weight[idx] into [b,c,h,w] x2 ----------------
__global__ void gather_k(const float* __restrict__ idxf, const float* __restrict__ w,
                         float* __restrict__ out0, float* __restrict__ out1) {
    int tid = blockIdx.x * 256 + threadIdx.x;
    int n   = tid & 65535;
    int c4  = tid >> 16;
    int code = (int)idxf[n];
    float4 v = *reinterpret_cast<const float4*>(w + (size_t)code * DDIM + c4 * 4);
    size_t off = (size_t)(n >> 12) * 1048576 + (size_t)c4 * 4 * 4096 + (n & 4095);
    out0[off]         = v.x;
    out0[off + 4096]  = v.y;
    out0[off + 8192]  = v.z;
    out0[off + 12288] = v.w;
    out1[off]         = v.x;
    out1[off + 4096]  = v.y;
    out1[off + 8192]  = v.z;
    out1[off + 12288] = v.w;
}

extern "C" void kernel_launch(void* const* d_in, const int* in_sizes, int n_in,
                              void* d_out, int out_size, void* d_ws, size_t ws_size,
                              hipStream_t stream) {
    const float* z = (const float*)d_in[0];
    const float* w = (const float*)d_in[1];
    float* out    = (float*)d_out;
    float* out0   = out;
    float* out1   = out + 16777216;
    float* outidx = out + 33554432;

    // scratch inside d_out (consumed before gather_k overwrites):
    f16x8* z16 = (f16x8*)out0;                              // 32MB in out0 (64MB region)
    char* s1b = (char*)out1;
    f16x8*   w16 = (f16x8*)s1b;                             // 512KB @ 0
    float*   wn  = (float*)(s1b + 1048576);                 // 4KB
    float*   btv = (float*)(s1b + 2097152);                 // 4MB  [16][65536]
    int*     bti = (int*)(s1b + 6291456);                   // 4MB  [16][65536]
    u64*     bmk = (u64*)(s1b + 10485760);                  // 8MB  [16][65536]
    unsigned char* flags = (unsigned char*)d_ws;            // 64KB

    wprep_k<<<32, 1024, 0, stream>>>(w, w16);
    wnorm_k<<<KCODES / 256, 256, 0, stream>>>(w, wn);
    zprep_k<<<NROWS * 32 / 256, 256, 0, stream>>>(z, z16);
    argmin_mfma_k<<<(NROWS / 128) * 8, 256, 0, stream>>>(z16, w16, wn, btv, bti, bmk);
    finalize_k<<<NROWS / 256, 256, 0, stream>>>(btv, bti, bmk, outidx, flags);
    rescue_k<<<NROWS / 16, 64, 0, stream>>>(z, w, wn, btv, bmk, flags, outidx);
    gather_k<<<NROWS * 64 / 256, 256, 0, stream>>>(outidx, w, out0, out1);
}

// Round 8
// 162.003 us; speedup vs baseline: 15.1636x; 1.0950x over previous
//
#include <hip/hip_runtime.h>

// VQ quantize: z [16,256,64,64] f32, weight [1024,256] f32.
// Outputs (f32, concat): quantized, straight_through (== quantized numerically), indices.
//
// zprep: z -> fp16 tiled [o][n][8].  wprep+wnorm: w -> fp16 (x1024, exact pow2) tiled;
//        wn = numpy-replicated fp32 ||w||^2.
// argmin: one fp16 MFMA pass (score err << np quant shift 6.1e-5), 2-phase pipelined
//         staging (dbuf LDS, counted drain), DPP argmin reduce, XCD-grouped blocks.
//         Per (row, 64-code entry): top-1 (value, code) + mask of codes within W of top-1.
// finrescue: per 16-row group: merge 16 entries (np first-index ties), flag margin<TAU
//         or in-entry popcount>1; flagged rows get bit-exact numpy rescore of ONLY the
//         candidate codes (validated r3-r7 numerics; s1 tree now wave-parallel).
// gather: codebook rows into both outputs.

#define NROWS 65536
#define DDIM 256
#define KCODES 1024
#define TAU 2e-4f
#define WWIN 2e-4f

typedef unsigned long long u64;
typedef _Float16 f16x8 __attribute__((ext_vector_type(8)));
typedef float f32x4 __attribute__((ext_vector_type(4)));

__device__ __forceinline__ void gld16(const void* g, void* l) {
    __builtin_amdgcn_global_load_lds((const __attribute__((address_space(1))) void*)g,
                                     (__attribute__((address_space(3))) void*)l, 16, 0, 0);
}

// numpy pairwise fp32 sum of 256 fl(x_i^2): 128+128 split, 8 accumulators per half,
// fixed combine tree. Bit-matches np.sum(flat*flat, axis=1) (validated r3..r7).
template <typename F>
__device__ __forceinline__ float np_pairwise256_sq(F get) {
    float half[2];
#pragma unroll
    for (int h = 0; h < 2; ++h) {
        float r[8];
#pragma unroll
        for (int j = 0; j < 8; ++j) { float v = get(h * 128 + j); r[j] = __fmul_rn(v, v); }
        for (int i = 8; i < 128; i += 8)
#pragma unroll
            for (int j = 0; j < 8; ++j) {
                float v = get(h * 128 + i + j);
                r[j] = __fadd_rn(r[j], __fmul_rn(v, v));
            }
        half[h] = __fadd_rn(__fadd_rn(__fadd_rn(r[0], r[1]), __fadd_rn(r[2], r[3])),
                            __fadd_rn(__fadd_rn(r[4], r[5]), __fadd_rn(r[6], r[7])));
    }
    return __fadd_rn(half[0], half[1]);
}

// ---------------- prep: z -> z16 tiled [o=0..31][n][8] ----------------
__global__ void zprep_k(const float* __restrict__ z, f16x8* __restrict__ z16) {
    int tid = blockIdx.x * 256 + threadIdx.x;
    int n = tid & 65535;
    int o = tid >> 16;
    const float* zp = z + (size_t)(n >> 12) * 1048576 + (n & 4095);
    f16x8 hv;
#pragma unroll
    for (int j = 0; j < 8; ++j) hv[j] = (_Float16)zp[(size_t)(o * 8 + j) * 4096];
    z16[(size_t)o * 65536 + n] = hv;
}

// ---------------- prep: w16 = fl16(1024*w) tiled [o][c][8]; wn = np ||w||^2 --------
__global__ void wprep_wnorm_k(const float* __restrict__ w, f16x8* __restrict__ w16,
                              float* __restrict__ wn) {
    int bid = blockIdx.x;
    if (bid < 32) {                      // wprep role
        int o = bid, c = threadIdx.x;    // 1024 threads
        const float* wp = w + (size_t)c * DDIM + o * 8;
        f16x8 hv;
#pragma unroll
        for (int j = 0; j < 8; ++j) hv[j] = (_Float16)(wp[j] * 1024.0f);  // pow2: exact
        w16[(size_t)o * 1024 + c] = hv;
    } else {                             // wnorm role: blocks 32..35, 256 active threads
        if (threadIdx.x < 256) {
            int k = (bid - 32) * 256 + threadIdx.x;
            const float* wp = w + (size_t)k * DDIM;
            wn[k] = np_pairwise256_sq([&](int i) { return wp[i]; });
        }
    }
}

// DPP argmin reduce stage (16-lane group): pure VALU, no LDS traffic.
#define DPP_ARGMIN(CTRL) {                                                              \
    float ov = __int_as_float(__builtin_amdgcn_mov_dpp(__float_as_int(bv), CTRL, 0xf, 0xf, false)); \
    int   oc = __builtin_amdgcn_mov_dpp(bc, CTRL, 0xf, 0xf, false);                     \
    if (ov < bv || (ov == bv && oc < bc)) { bv = ov; bc = oc; } }

// ---------------- fp16-MFMA distance; pipelined staging; per-entry top1 + mask ------
// Block: 128 rows x 128 codes; 4 waves 2x2 (wm row-half, wn_ code-half), 64x64 each.
// XCD remap: all 8 cb-blocks of one row-group land on the same XCD (L2 A-reuse).
__launch_bounds__(256, 2)
__global__ void argmin_mfma_k(const f16x8* __restrict__ z16, const f16x8* __restrict__ w16,
                              const float* __restrict__ wn,
                              float* __restrict__ btv, int* __restrict__ bti,
                              u64* __restrict__ bmk) {
    __shared__ char arena[65536];               // 2 x (A 16KB | B 16KB)
    const int t = threadIdx.x;
    const int lane = t & 63;
    const int l15 = lane & 15, l4 = lane >> 4;
    const int wid = t >> 6;                     // 0..3
    const int wm = wid >> 1, wn_ = wid & 1;
    const int p = blockIdx.x;
    const int cb = (p >> 3) & 7;                // remap: same-n0 group shares XCD
    const int n0 = ((((p & 7) << 6) | (p >> 6)) << 7);
    const int c0 = cb << 7;

    f32x4 acc[4][4];
#pragma unroll
    for (int mt = 0; mt < 4; ++mt)
#pragma unroll
        for (int nt = 0; nt < 4; ++nt) acc[mt][nt] = f32x4{0.f, 0.f, 0.f, 0.f};

    auto STAGE = [&](int s, int buf) {
        char* lA = arena + buf * 32768;
        char* lB = lA + 16384;
#pragma unroll
        for (int q = 0; q < 4; ++q) {
            int i = wid * 4 + q;
            int o = s * 8 + (i >> 1);
            int half = i & 1;
            gld16((const char*)z16 + (size_t)(o * 65536 + n0 + half * 64) * 16 + lane * 16,
                  lA + i * 1024);
            gld16((const char*)w16 + (size_t)(o * 1024 + c0 + half * 64) * 16 + lane * 16,
                  lB + i * 1024);
        }
    };
    auto COMPUTE = [&](int buf) {
        char* lA = arena + buf * 32768;
        char* lB = lA + 16384;
#pragma unroll
        for (int j = 0; j < 2; ++j) {
            f16x8 a[4], b[4];
            const char* pa = lA + (j * 4 + l4) * 2048 + (wm * 64 + l15) * 16;
#pragma unroll
            for (int mt = 0; mt < 4; ++mt) a[mt] = *reinterpret_cast<const f16x8*>(pa + mt * 256);
            const char* pb = lB + (j * 4 + l4) * 2048 + (wn_ * 64 + l15) * 16;
#pragma unroll
            for (int nt = 0; nt < 4; ++nt) b[nt] = *reinterpret_cast<const f16x8*>(pb + nt * 256);
#pragma unroll
            for (int mt = 0; mt < 4; ++mt)
#pragma unroll
                for (int nt = 0; nt < 4; ++nt)
                    acc[mt][nt] = __builtin_amdgcn_mfma_f32_16x16x32_f16(a[mt], b[nt], acc[mt][nt], 0, 0, 0);
        }
    };

    // 2-phase pipeline: STAGE(next) before COMPUTE(cur); one vmcnt(0)+barrier per step.
    STAGE(0, 0);
    asm volatile("s_waitcnt vmcnt(0)" ::: "memory");
    __builtin_amdgcn_s_barrier();
    STAGE(1, 1);
    COMPUTE(0);
    asm volatile("s_waitcnt vmcnt(0)" ::: "memory");
    __builtin_amdgcn_s_barrier();
    STAGE(2, 0);
    COMPUTE(1);
    asm volatile("s_waitcnt vmcnt(0)" ::: "memory");
    __builtin_amdgcn_s_barrier();
    STAGE(3, 1);
    COMPUTE(0);
    asm volatile("s_waitcnt vmcnt(0)" ::: "memory");
    __builtin_amdgcn_s_barrier();
    COMPUTE(1);

    // ---- epilogue: s = wn - 2^-9 m'; per (row, entry e=cb*2+wn_): top1 + W-mask ----
    float wnv[4];
#pragma unroll
    for (int nt = 0; nt < 4; ++nt) wnv[nt] = wn[c0 + wn_ * 64 + nt * 16 + l15];
    const int ebase = ((cb << 1) | wn_) << 16;

#pragma unroll
    for (int mt = 0; mt < 4; ++mt) {
#pragma unroll
        for (int r = 0; r < 4; ++r) {
            // C/D layout: col = lane&15, row = (lane>>4)*4 + r
            float s[4];
            float bv = 3.4e38f;
            int   bc = 0;
#pragma unroll
            for (int nt = 0; nt < 4; ++nt) {
                s[nt] = fmaf(-0.001953125f, acc[mt][nt][r], wnv[nt]);   // -2^-9 (w x1024)
                if (s[nt] < bv) { bv = s[nt]; bc = c0 + wn_ * 64 + nt * 16 + l15; }
            }
            // 16-lane argmin via DPP (VALU): xor1, xor2, half-mirror, mirror
            DPP_ARGMIN(0xB1)    // quad_perm [1,0,3,2]
            DPP_ARGMIN(0x4E)    // quad_perm [2,3,0,1]
            DPP_ARGMIN(0x141)   // row_half_mirror
            DPP_ARGMIN(0x140)   // row_mirror
            u64 msk = 0;
#pragma unroll
            for (int nt = 0; nt < 4; ++nt) {    // wave ballot; 16-bit slice per l4 group
                u64 bal = __ballot(s[nt] < bv + WWIN);
                msk |= ((bal >> (16 * l4)) & 0xFFFFull) << (16 * nt);
            }
            if (l15 == 0) {
                int row = wm * 64 + mt * 16 + l4 * 4 + r;
                btv[ebase + n0 + row] = bv;
                bti[ebase + n0 + row] = bc;
                bmk[ebase + n0 + row] = msk;
            }
        }
    }
}

// ---------------- finalize+rescue fused: per 16-row group, 64 threads ----------------
__global__ void finrescue_k(const float* __restrict__ z, const float* __restrict__ w,
                            const float* __restrict__ s2,
                            const float* __restrict__ btv, const int* __restrict__ bti,
                            const u64* __restrict__ bmk, float* __restrict__ idxf_out) {
    __shared__ float zsh[16][256];              // 16KB panel
    const int lane = threadIdx.x;               // 0..63
    const int n0 = blockIdx.x * 16;
    const int r = lane >> 2;                    // row 0..15
    const int eq = lane & 3;                    // entry quarter
    const int n = n0 + r;

    // merge 16 entry-top1s (ascending e within lane, then xor-merge with (v,c) ties)
    float bv = 3.4e38f, b2 = 3.4e38f;
    int bi = 0, be = 0;
#pragma unroll
    for (int i = 0; i < 4; ++i) {
        int e = eq * 4 + i;
        float v = btv[(e << 16) + n];
        int c = bti[(e << 16) + n];
        if (v < bv || (v == bv && c < bi)) { b2 = bv; bv = v; bi = c; be = e; }
        else b2 = fminf(b2, v);
    }
#pragma unroll
    for (int m = 1; m < 4; m <<= 1) {
        float ov = __shfl_xor(bv, m), o2 = __shfl_xor(b2, m);
        int oc = __shfl_xor(bi, m), oe = __shfl_xor(be, m);
        if (ov < bv || (ov == bv && oc < bi)) { b2 = fminf(bv, o2); bv = ov; bi = oc; be = oe; }
        else b2 = fminf(b2, ov);
    }
    u64 wmask = bmk[((u64)be << 16) + n];
    bool flag = (__popcll(wmask) > 1) || (b2 - bv < TAU);
    if (eq == 0) idxf_out[n] = (float)bi;
    u64 fb = __ballot(flag);
    if ((fb & 0x1111111111111111ull) == 0) return;

    // cooperative z panel (rows share 64B lines)
    const float* zb = z + (size_t)(n0 >> 12) * 1048576 + (n0 & 4095);
#pragma unroll
    for (int it = 0; it < 16; ++it) {
        int d = it * 16 + (lane >> 2);
        float4 v = *reinterpret_cast<const float4*>(zb + (size_t)d * 4096 + (lane & 3) * 4);
        zsh[(lane & 3) * 4 + 0][d] = v.x;
        zsh[(lane & 3) * 4 + 1][d] = v.y;
        zsh[(lane & 3) * 4 + 2][d] = v.z;
        zsh[(lane & 3) * 4 + 3][d] = v.w;
    }
    __syncthreads();

    for (int r2 = 0; r2 < 16; ++r2) {
        if (!((fb >> (r2 * 4)) & 1)) continue;
        int nn = n0 + r2;
        // s1: numpy pairwise tree, wave-parallel (lanes (h,j) own accumulators; exact tree)
        int hh = (lane >> 3) & 1, jj = lane & 7;
        float v0 = zsh[r2][hh * 128 + jj];
        float accj = __fmul_rn(v0, v0);
#pragma unroll
        for (int i = 1; i < 16; ++i) {
            float v2 = zsh[r2][hh * 128 + i * 8 + jj];
            accj = __fadd_rn(accj, __fmul_rn(v2, v2));
        }
        float a1 = __fadd_rn(accj, __shfl_xor(accj, 1));   // r0+r1 (commutative = exact)
        float a2 = __fadd_rn(a1, __shfl_xor(a1, 2));       // (r0+r1)+(r2+r3)
        float a4 = __fadd_rn(a2, __shfl_xor(a2, 4));       // half[h]
        float s1 = __fadd_rn(a4, __shfl_xor(a4, 8));       // half0+half1

        float gv = 3.4e38f;
#pragma unroll
        for (int e = 0; e < 16; ++e) gv = fminf(gv, btv[(e << 16) + nn]);

        float zr0 = zsh[r2][lane * 4 + 0], zr1 = zsh[r2][lane * 4 + 1];
        float zr2 = zsh[r2][lane * 4 + 2], zr3 = zsh[r2][lane * 4 + 3];
        float bv2 = 3.4e38f;
        int   bi2 = 0;
        for (int e = 0; e < 16; ++e) {          // ascending codes -> first-index ties
            float tv = btv[(e << 16) + nn];
            if (tv <= gv + TAU) {
                u64 m = bmk[((u64)e << 16) + nn];
                while (m) {
                    int k = __ffsll((long long)m) - 1;
                    m &= m - 1;
                    int c = e * 64 + k;
                    const float* wp = w + (size_t)c * DDIM + lane * 4;
                    double md = 0.0;
                    md = fma((double)zr0, (double)wp[0], md);
                    md = fma((double)zr1, (double)wp[1], md);
                    md = fma((double)zr2, (double)wp[2], md);
                    md = fma((double)zr3, (double)wp[3], md);
#pragma unroll
                    for (int mm = 1; mm < 64; mm <<= 1) md += __shfl_xor(md, mm);
                    float dq = __fadd_rn((float)((double)s1 - 2.0 * md), s2[c]);
                    if (dq < bv2) { bv2 = dq; bi2 = c; }
                }
            }
        }
        if (lane == 0) idxf_out[nn] = (float)bi2;
    }
}

// ---------------- gather quantized = weight[idx] into [b,c,h,w] x2 ----------------
__global__ void gather_k(const float* __restrict__ idxf, const float* __restrict__ w,
                         float* __restrict__ out0, float* __restrict__ out1) {
    int tid = blockIdx.x * 256 + threadIdx.x;
    int n   = tid & 65535;
    int c4  = tid >> 16;
    int code = (int)idxf[n];
    float4 v = *reinterpret_cast<const float4*>(w + (size_t)code * DDIM + c4 * 4);
    size_t off = (size_t)(n >> 12) * 1048576 + (size_t)c4 * 4 * 4096 + (n & 4095);
    out0[off]         = v.x;
    out0[off + 4096]  = v.y;
    out0[off + 8192]  = v.z;
    out0[off + 12288] = v.w;
    out1[off]         = v.x;
    out1[off + 4096]  = v.y;
    out1[off + 8192]  = v.z;
    out1[off + 12288] = v.w;
}

extern "C" void kernel_launch(void* const* d_in, const int* in_sizes, int n_in,
                              void* d_out, int out_size, void* d_ws, size_t ws_size,
                              hipStream_t stream) {
    const float* z = (const float*)d_in[0];
    const float* w = (const float*)d_in[1];
    float* out    = (float*)d_out;
    float* out0   = out;
    float* out1   = out + 16777216;
    float* outidx = out + 33554432;

    // scratch inside d_out (consumed before gather_k overwrites):
    f16x8* z16 = (f16x8*)out0;                              // 32MB in out0 (64MB region)
    char* s1b = (char*)out1;
    f16x8* w16 = (f16x8*)s1b;                               // 512KB
    float* wn  = (float*)(s1b + 1048576);                   // 4KB
    float* btv = (float*)(s1b + 2097152);                   // 4MB  [16][65536]
    int*   bti = (int*)(s1b + 6291456);                     // 4MB  [16][65536]
    u64*   bmk = (u64*)(s1b + 10485760);                    // 8MB  [16][65536]

    wprep_wnorm_k<<<36, 1024, 0, stream>>>(w, w16, wn);
    zprep_k<<<NROWS * 32 / 256, 256, 0, stream>>>(z, z16);
    argmin_mfma_k<<<(NROWS / 128) * 8, 256, 0, stream>>>(z16, w16, wn, btv, bti, bmk);
    finrescue_k<<<NROWS / 16, 64, 0, stream>>>(z, w, wn, btv, bti, bmk, outidx);
    gather_k<<<NROWS * 64 / 256, 256, 0, stream>>>(outidx, w, out0, out1);
}

// Round 9
// 128.919 us; speedup vs baseline: 19.0550x; 1.2566x over previous
//
#include <hip/hip_runtime.h>

// VQ quantize: z [16,256,64,64] f32, weight [1024,256] f32.
// Outputs (f32, concat): quantized, straight_through (== quantized numerically), indices.
//
// prep: z -> fp16 tiled [o][n][8]; w -> fp16 (x1024, exact pow2) tiled; wn = np ||w||^2.
// argmin: one fp16 MFMA pass, BK=32 x 8 steps, 2x16KB LDS double-buffer 2-phase
//         pipeline, XCD-grouped blocks (L2-resident A/B), value-only DPP min epilogue;
//         per (row, 64-code entry): top-1 value + W-window mask; index = ctz(mask)
//         (exact whenever unflagged: popcount>1 => flagged => rescue recomputes).
// finrescue: merge 16 entries (np first-index ties), flag margin<TAU or popcount>1;
//         flagged rows get bit-exact numpy rescore of ONLY candidate codes (r3-r8).
// gather: codebook rows into both outputs.

#define NROWS 65536
#define DDIM 256
#define KCODES 1024
#define TAU 2e-4f
#define WWIN 2e-4f

typedef unsigned long long u64;
typedef _Float16 f16x8 __attribute__((ext_vector_type(8)));
typedef float f32x4 __attribute__((ext_vector_type(4)));

__device__ __forceinline__ void gld16(const void* g, void* l) {
    __builtin_amdgcn_global_load_lds((const __attribute__((address_space(1))) void*)g,
                                     (__attribute__((address_space(3))) void*)l, 16, 0, 0);
}

// numpy pairwise fp32 sum of 256 fl(x_i^2): 128+128 split, 8 accumulators per half,
// fixed combine tree. Bit-matches np.sum(flat*flat, axis=1) (validated r3..r8).
template <typename F>
__device__ __forceinline__ float np_pairwise256_sq(F get) {
    float half[2];
#pragma unroll
    for (int h = 0; h < 2; ++h) {
        float r[8];
#pragma unroll
        for (int j = 0; j < 8; ++j) { float v = get(h * 128 + j); r[j] = __fmul_rn(v, v); }
        for (int i = 8; i < 128; i += 8)
#pragma unroll
            for (int j = 0; j < 8; ++j) {
                float v = get(h * 128 + i + j);
                r[j] = __fadd_rn(r[j], __fmul_rn(v, v));
            }
        half[h] = __fadd_rn(__fadd_rn(__fadd_rn(r[0], r[1]), __fadd_rn(r[2], r[3])),
                            __fadd_rn(__fadd_rn(r[4], r[5]), __fadd_rn(r[6], r[7])));
    }
    return __fadd_rn(half[0], half[1]);
}

// ---------------- fused prep: zprep (blocks 0..8191) | wprep (..8319) | wnorm (..8323)
__global__ void prep_k(const float* __restrict__ z, const float* __restrict__ w,
                       f16x8* __restrict__ z16, f16x8* __restrict__ w16,
                       float* __restrict__ wn) {
    int bid = blockIdx.x;
    if (bid < 8192) {
        int tid = bid * 256 + threadIdx.x;
        int n = tid & 65535;
        int o = tid >> 16;
        const float* zp = z + (size_t)(n >> 12) * 1048576 + (n & 4095);
        f16x8 hv;
#pragma unroll
        for (int j = 0; j < 8; ++j) hv[j] = (_Float16)zp[(size_t)(o * 8 + j) * 4096];
        z16[(size_t)o * 65536 + n] = hv;
    } else if (bid < 8320) {
        int idx = (bid - 8192) * 256 + threadIdx.x;   // 32768 items
        int o = idx >> 10, c = idx & 1023;
        const float* wp = w + (size_t)c * DDIM + o * 8;
        f16x8 hv;
#pragma unroll
        for (int j = 0; j < 8; ++j) hv[j] = (_Float16)(wp[j] * 1024.0f);  // pow2: exact
        w16[(size_t)o * 1024 + c] = hv;
    } else {
        int k = (bid - 8320) * 256 + threadIdx.x;
        const float* wp = w + (size_t)k * DDIM;
        wn[k] = np_pairwise256_sq([&](int i) { return wp[i]; });
    }
}

// DPP min stage (16-lane group): pure VALU.
#define DPP_MIN(CTRL) {                                                                 \
    float ov = __int_as_float(__builtin_amdgcn_mov_dpp(__float_as_int(bv), CTRL, 0xf, 0xf, false)); \
    bv = fminf(bv, ov); }

// ---------------- fp16-MFMA distance; BK=32 dbuf pipeline; per-entry top1 + mask ----
// Block: 128 rows x 128 codes; 4 waves 2x2 (wm row-half, wn_ code-half), 64x64 each.
// XCD remap: the 8 cb-blocks of one row-group land on the same XCD (L2 A-reuse).
__launch_bounds__(256, 4)
__global__ void argmin_mfma_k(const f16x8* __restrict__ z16, const f16x8* __restrict__ w16,
                              const float* __restrict__ wn,
                              float* __restrict__ btv, int* __restrict__ bti,
                              u64* __restrict__ bmk) {
    __shared__ char arena[32768];               // 2 x (A 8KB | B 8KB)
    const int t = threadIdx.x;
    const int lane = t & 63;
    const int l15 = lane & 15, l4 = lane >> 4;
    const int wid = t >> 6;                     // 0..3
    const int wm = wid >> 1, wn_ = wid & 1;
    const int p = blockIdx.x;
    const int cb = (p >> 3) & 7;                // remap: same-n0 group shares XCD
    const int n0 = ((((p & 7) << 6) | (p >> 6)) << 7);
    const int c0 = cb << 7;

    f32x4 acc[4][4];
#pragma unroll
    for (int mt = 0; mt < 4; ++mt)
#pragma unroll
        for (int nt = 0; nt < 4; ++nt) acc[mt][nt] = f32x4{0.f, 0.f, 0.f, 0.f};

    // STAGE(s,buf): 4 octets (BK=32): A 8KB + B 8KB; wave wid: 2 A-chunks + 2 B-chunks.
    auto STAGE = [&](int s, int buf) {
        char* lA = arena + buf * 16384;
        char* lB = lA + 8192;
        int ia = wid * 2;
#pragma unroll
        for (int q = 0; q < 2; ++q) {
            int i = ia + q;                     // chunk 0..7
            int o = s * 4 + (i >> 1);
            int half = i & 1;
            gld16((const char*)z16 + (size_t)(o * 65536 + n0 + half * 64 + lane) * 16,
                  lA + i * 1024);
            gld16((const char*)w16 + (size_t)(o * 1024 + c0 + half * 64 + lane) * 16,
                  lB + i * 1024);
        }
    };
    auto COMPUTE = [&](int buf) {
        char* lA = arena + buf * 16384;
        char* lB = lA + 8192;
        f16x8 a[4], b[4];
        const char* pa = lA + l4 * 2048 + (wm * 64 + l15) * 16;
#pragma unroll
        for (int mt = 0; mt < 4; ++mt) a[mt] = *reinterpret_cast<const f16x8*>(pa + mt * 256);
        const char* pb = lB + l4 * 2048 + (wn_ * 64 + l15) * 16;
#pragma unroll
        for (int nt = 0; nt < 4; ++nt) b[nt] = *reinterpret_cast<const f16x8*>(pb + nt * 256);
#pragma unroll
        for (int mt = 0; mt < 4; ++mt)
#pragma unroll
            for (int nt = 0; nt < 4; ++nt)
                acc[mt][nt] = __builtin_amdgcn_mfma_f32_16x16x32_f16(a[mt], b[nt], acc[mt][nt], 0, 0, 0);
    };

    // 2-phase pipeline: STAGE(s+1) issued before COMPUTE(s); one vmcnt(0)+barrier/step.
    STAGE(0, 0);
    asm volatile("s_waitcnt vmcnt(0)" ::: "memory");
    __builtin_amdgcn_s_barrier();
#pragma unroll
    for (int s = 0; s < 7; ++s) {
        STAGE(s + 1, (s + 1) & 1);
        COMPUTE(s & 1);
        asm volatile("s_waitcnt vmcnt(0)" ::: "memory");
        __builtin_amdgcn_s_barrier();
    }
    COMPUTE(1);

    // ---- epilogue: s = wn - 2^-9 m'; per (row, entry e=cb*2+wn_): top1 + W-mask ----
    float wnv[4];
#pragma unroll
    for (int nt = 0; nt < 4; ++nt) wnv[nt] = wn[c0 + wn_ * 64 + nt * 16 + l15];
    const int ebase = ((cb << 1) | wn_) << 16;
    const int ecode = ((cb << 1) | wn_) << 6;

#pragma unroll
    for (int mt = 0; mt < 4; ++mt) {
#pragma unroll
        for (int r = 0; r < 4; ++r) {
            // C/D layout: col = lane&15, row = (lane>>4)*4 + r
            float s0 = fmaf(-0.001953125f, acc[mt][0][r], wnv[0]);   // -2^-9 (w x1024)
            float s1 = fmaf(-0.001953125f, acc[mt][1][r], wnv[1]);
            float s2 = fmaf(-0.001953125f, acc[mt][2][r], wnv[2]);
            float s3 = fmaf(-0.001953125f, acc[mt][3][r], wnv[3]);
            float bv = fminf(fminf(s0, s1), fminf(s2, s3));
            DPP_MIN(0xB1)      // quad_perm [1,0,3,2]
            DPP_MIN(0x4E)      // quad_perm [2,3,0,1]
            DPP_MIN(0x141)     // row_half_mirror
            DPP_MIN(0x140)     // row_mirror  -> bv = 16-lane-group min
            float thr = bv + WWIN;
            u64 b0 = __ballot(s0 < thr), b1 = __ballot(s1 < thr);
            u64 b2 = __ballot(s2 < thr), b3 = __ballot(s3 < thr);
            int sh = 16 * l4;
            u64 msk = ((b0 >> sh) & 0xFFFFull)
                    | (((b1 >> sh) & 0xFFFFull) << 16)
                    | (((b2 >> sh) & 0xFFFFull) << 32)
                    | (((b3 >> sh) & 0xFFFFull) << 48);
            if (l15 == 0) {
                int row = wm * 64 + mt * 16 + l4 * 4 + r;
                btv[ebase + n0 + row] = bv;
                // exact argmin whenever popcount==1 (else row is flagged & rescued)
                bti[ebase + n0 + row] = ecode + (int)(__ffsll((long long)msk) - 1);
                bmk[ebase + n0 + row] = msk;
            }
        }
    }
}

// ---------------- finalize+rescue fused: per 16-row group, 64 threads ----------------
__global__ void finrescue_k(const float* __restrict__ z, const float* __restrict__ w,
                            const float* __restrict__ s2,
                            const float* __restrict__ btv, const int* __restrict__ bti,
                            const u64* __restrict__ bmk, float* __restrict__ idxf_out) {
    __shared__ float zsh[16][256];              // 16KB panel
    const int lane = threadIdx.x;               // 0..63
    const int n0 = blockIdx.x * 16;
    const int r = lane >> 2;                    // row 0..15
    const int eq = lane & 3;                    // entry quarter
    const int n = n0 + r;

    // merge 16 entry-top1s (ascending e within lane, then xor-merge with (v,c) ties)
    float bv = 3.4e38f, b2 = 3.4e38f;
    int bi = 0, be = 0;
#pragma unroll
    for (int i = 0; i < 4; ++i) {
        int e = eq * 4 + i;
        float v = btv[(e << 16) + n];
        int c = bti[(e << 16) + n];
        if (v < bv || (v == bv && c < bi)) { b2 = bv; bv = v; bi = c; be = e; }
        else b2 = fminf(b2, v);
    }
#pragma unroll
    for (int m = 1; m < 4; m <<= 1) {
        float ov = __shfl_xor(bv, m), o2 = __shfl_xor(b2, m);
        int oc = __shfl_xor(bi, m), oe = __shfl_xor(be, m);
        if (ov < bv || (ov == bv && oc < bi)) { b2 = fminf(bv, o2); bv = ov; bi = oc; be = oe; }
        else b2 = fminf(b2, ov);
    }
    u64 wmask = bmk[((u64)be << 16) + n];
    bool flag = (__popcll(wmask) > 1) || (b2 - bv < TAU);
    if (eq == 0) idxf_out[n] = (float)bi;
    u64 fb = __ballot(flag);
    if ((fb & 0x1111111111111111ull) == 0) return;

    // cooperative z panel (rows share 64B lines)
    const float* zb = z + (size_t)(n0 >> 12) * 1048576 + (n0 & 4095);
#pragma unroll
    for (int it = 0; it < 16; ++it) {
        int d = it * 16 + (lane >> 2);
        float4 v = *reinterpret_cast<const float4*>(zb + (size_t)d * 4096 + (lane & 3) * 4);
        zsh[(lane & 3) * 4 + 0][d] = v.x;
        zsh[(lane & 3) * 4 + 1][d] = v.y;
        zsh[(lane & 3) * 4 + 2][d] = v.z;
        zsh[(lane & 3) * 4 + 3][d] = v.w;
    }
    __syncthreads();

    for (int r2 = 0; r2 < 16; ++r2) {
        if (!((fb >> (r2 * 4)) & 1)) continue;
        int nn = n0 + r2;
        // s1: numpy pairwise tree, wave-parallel exact (lanes (h,j) own accumulators)
        int hh = (lane >> 3) & 1, jj = lane & 7;
        float v0 = zsh[r2][hh * 128 + jj];
        float accj = __fmul_rn(v0, v0);
#pragma unroll
        for (int i = 1; i < 16; ++i) {
            float v2 = zsh[r2][hh * 128 + i * 8 + jj];
            accj = __fadd_rn(accj, __fmul_rn(v2, v2));
        }
        float a1 = __fadd_rn(accj, __shfl_xor(accj, 1));
        float a2 = __fadd_rn(a1, __shfl_xor(a1, 2));
        float a4 = __fadd_rn(a2, __shfl_xor(a2, 4));
        float s1 = __fadd_rn(a4, __shfl_xor(a4, 8));

        float gv = __shfl(bv, r2 * 4);          // global min of row r2 (from merge phase)

        float zr0 = zsh[r2][lane * 4 + 0], zr1 = zsh[r2][lane * 4 + 1];
        float zr2 = zsh[r2][lane * 4 + 2], zr3 = zsh[r2][lane * 4 + 3];
        float bv2 = 3.4e38f;
        int   bi2 = 0;
        for (int e = 0; e < 16; ++e) {          // ascending codes -> first-index ties
            float tv = btv[(e << 16) + nn];
            if (tv <= gv + TAU) {
                u64 m = bmk[((u64)e << 16) + nn];
                while (m) {
                    int k = __ffsll((long long)m) - 1;
                    m &= m - 1;
                    int c = e * 64 + k;
                    const float* wp = w + (size_t)c * DDIM + lane * 4;
                    double md = 0.0;
                    md = fma((double)zr0, (double)wp[0], md);
                    md = fma((double)zr1, (double)wp[1], md);
                    md = fma((double)zr2, (double)wp[2], md);
                    md = fma((double)zr3, (double)wp[3], md);
#pragma unroll
                    for (int mm = 1; mm < 64; mm <<= 1) md += __shfl_xor(md, mm);
                    float dq = __fadd_rn((float)((double)s1 - 2.0 * md), s2[c]);
                    if (dq < bv2) { bv2 = dq; bi2 = c; }
                }
            }
        }
        if (lane == 0) idxf_out[nn] = (float)bi2;
    }
}

// ---------------- gather quantized = weight[idx] into [b,c,h,w] x2 ----------------
__global__ void gather_k(const float* __restrict__ idxf, const float* __restrict__ w,
                         float* __restrict__ out0, float* __restrict__ out1) {
    int tid = blockIdx.x * 256 + threadIdx.x;
    int n   = tid & 65535;
    int c4  = tid >> 16;
    int code = (int)idxf[n];
    float4 v = *reinterpret_cast<const float4*>(w + (size_t)code * DDIM + c4 * 4);
    size_t off = (size_t)(n >> 12) * 1048576 + (size_t)c4 * 4 * 4096 + (n & 4095);
    out0[off]         = v.x;
    out0[off + 4096]  = v.y;
    out0[off + 8192]  = v.z;
    out0[off + 12288] = v.w;
    out1[off]         = v.x;
    out1[off + 4096]  = v.y;
    out1[off + 8192]  = v.z;
    out1[off + 12288] = v.w;
}

extern "C" void kernel_launch(void* const* d_in, const int* in_sizes, int n_in,
                              void* d_out, int out_size, void* d_ws, size_t ws_size,
                              hipStream_t stream) {
    const float* z = (const float*)d_in[0];
    const float* w = (const float*)d_in[1];
    float* out    = (float*)d_out;
    float* out0   = out;
    float* out1   = out + 16777216;
    float* outidx = out + 33554432;

    // scratch inside d_out (consumed before gather_k overwrites):
    f16x8* z16 = (f16x8*)out0;                              // 32MB in out0 (64MB region)
    char* s1b = (char*)out1;
    f16x8* w16 = (f16x8*)s1b;                               // 512KB
    float* wn  = (float*)(s1b + 1048576);                   // 4KB
    float* btv = (float*)(s1b + 2097152);                   // 4MB  [16][65536]
    int*   bti = (int*)(s1b + 6291456);                     // 4MB  [16][65536]
    u64*   bmk = (u64*)(s1b + 10485760);                    // 8MB  [16][65536]

    prep_k<<<8324, 256, 0, stream>>>(z, w, z16, w16, wn);
    argmin_mfma_k<<<(NROWS / 128) * 8, 256, 0, stream>>>(z16, w16, wn, btv, bti, bmk);
    finrescue_k<<<NROWS / 16, 64, 0, stream>>>(z, w, wn, btv, bti, bmk, outidx);
    gather_k<<<NROWS * 64 / 256, 256, 0, stream>>>(outidx, w, out0, out1);
}